// Round 12
// baseline (323.360 us; speedup 1.0000x reference)
//
#include <hip/hip_runtime.h>
#include <math.h>

#define N_NODES 2048
#define D_MODEL 256
#define D_FEAT 128
#define NHEAD 8
#define DH 32
#define NLAYER 2
#define NEDGE 65536
#define D_FF 1024
#define D_OUT 128
#define MAXDEG 512
#define JSPLIT 8

typedef __attribute__((ext_vector_type(8))) short short8;
typedef __attribute__((ext_vector_type(4))) float f32x4;
typedef __attribute__((ext_vector_type(4))) unsigned short u16x4;

__device__ __forceinline__ unsigned short f2bf(float f) {
    unsigned u = __float_as_uint(f);
    unsigned r = (u + 0x7FFFu + ((u >> 16) & 1u)) >> 16;
    return (unsigned short)r;
}

template <int CTRL>
__device__ __forceinline__ float dpp_ror(float x) {
    return __int_as_float(__builtin_amdgcn_update_dpp(0, __float_as_int(x), CTRL, 0xf, 0xf, false));
}

// ---------------- mega prep: bucket table + zeroing + all weight transposes ----------------
__device__ __forceinline__ void wt_tile(const float* __restrict__ W, unsigned short* __restrict__ Wt,
                                        int K, int Nc, int n0, int k0, int tid,
                                        unsigned short (*tile)[33]) {
    int r = tid >> 3, cg = (tid & 7) * 4;
    float4 w4 = *(const float4*)&W[(size_t)(k0 + r) * Nc + n0 + cg];
    tile[r][cg + 0] = f2bf(w4.x); tile[r][cg + 1] = f2bf(w4.y);
    tile[r][cg + 2] = f2bf(w4.z); tile[r][cg + 3] = f2bf(w4.w);
    __syncthreads();
    int c = tid >> 3, rg = (tid & 7) * 4;
    u16x4 o;
    #pragma unroll
    for (int j = 0; j < 4; j++) o[j] = tile[rg + j][c];
    *(u16x4*)&Wt[(size_t)(n0 + c) * K + k0 + rg] = o;
}

__global__ void mega_prep_kernel(const float* __restrict__ pos, unsigned char* __restrict__ bucket,
                                 unsigned* __restrict__ hist, int* __restrict__ deg_out,
                                 int* __restrict__ deg_in,
                                 const float* __restrict__ Wq, const float* __restrict__ Wk,
                                 const float* __restrict__ Wv, const float* __restrict__ Wo,
                                 const float* __restrict__ W1, const float* __restrict__ W2,
                                 const float* __restrict__ W_emb, const float* __restrict__ W_out,
                                 const float* __restrict__ bq, const float* __restrict__ bk,
                                 const float* __restrict__ bv,
                                 unsigned short* __restrict__ qkvt, unsigned short* __restrict__ wot,
                                 unsigned short* __restrict__ w1t, unsigned short* __restrict__ w2t,
                                 unsigned short* __restrict__ wembt, unsigned short* __restrict__ woutt,
                                 float* __restrict__ bqkv) {
    __shared__ unsigned short tile[32][33];
    int b = blockIdx.x, tid = threadIdx.x;
    if (b < 4096) {                      // bucket table (N*N/4 u32 elements over 4096 blocks)
        int i = b * 256 + tid;
        float4 p = *(const float4*)&pos[(size_t)i * 4];
        unsigned b0 = (unsigned)fminf(fmaxf(p.x * 10.f + 0.5f, 0.f), 10.f);
        unsigned b1 = (unsigned)fminf(fmaxf(p.y * 10.f + 0.5f, 0.f), 10.f);
        unsigned b2 = (unsigned)fminf(fmaxf(p.z * 10.f + 0.5f, 0.f), 10.f);
        unsigned b3 = (unsigned)fminf(fmaxf(p.w * 10.f + 0.5f, 0.f), 10.f);
        ((unsigned*)bucket)[i] = b0 | (b1 << 8) | (b2 << 16) | (b3 << 24);
        if (b < 64) {                    // zero hist: 64 blocks x 1024 u32
            #pragma unroll
            for (int k = 0; k < 4; k++) hist[b * 1024 + k * 256 + tid] = 0;
        } else if (b == 64) {            // zero BOTH degree arrays
            #pragma unroll
            for (int k = 0; k < 8; k++) deg_out[k * 256 + tid] = 0;
            #pragma unroll
            for (int k = 0; k < 8; k++) deg_in[k * 256 + tid] = 0;
        }
        return;
    }
    int bb = b - 4096;
    if (bb < 512) {
        int z = bb >> 6, t = bb & 63;
        int l = z >> 2, which = z & 3;
        const float* W = (which == 0 ? Wq : which == 1 ? Wk : which == 2 ? Wv : Wo) + (size_t)l * 65536;
        unsigned short* dst = (which < 3) ? qkvt + (size_t)l * 196608 + which * 65536
                                          : wot + (size_t)l * 65536;
        wt_tile(W, dst, 256, 256, (t & 7) * 32, (t >> 3) * 32, tid, tile);
    } else if (bb < 1024) {
        int b2 = bb - 512, l = b2 >> 8, t = b2 & 255;
        wt_tile(W1 + (size_t)l * D_MODEL * D_FF, w1t + (size_t)l * D_MODEL * D_FF,
                D_MODEL, D_FF, (t & 31) * 32, (t >> 5) * 32, tid, tile);
    } else if (bb < 1536) {
        int b3 = bb - 1024, l = b3 >> 8, t = b3 & 255;
        wt_tile(W2 + (size_t)l * D_FF * D_MODEL, w2t + (size_t)l * D_FF * D_MODEL,
                D_FF, D_MODEL, (t & 7) * 32, (t >> 3) * 32, tid, tile);
    } else if (bb < 1568) {
        int b4 = bb - 1536;
        wt_tile(W_emb, wembt, D_FEAT, D_MODEL, (b4 & 7) * 32, (b4 >> 3) * 32, tid, tile);
    } else if (bb < 1600) {
        int b5 = bb - 1568;
        wt_tile(W_out, woutt, D_MODEL, D_OUT, (b5 & 3) * 32, (b5 >> 2) * 32, tid, tile);
    } else {
        int i = (bb - 1600) * 256 + tid;
        if (i < NLAYER * 768) {
            int l = i / 768, j = i % 768;
            const float* src = j < 256 ? bq : j < 512 ? bk : bv;
            bqkv[i] = src[l * 256 + (j & 255)];
        }
    }
}

// ---------------- degree + edge histogram ----------------
__global__ void degree_hist_kernel(const int* __restrict__ ei,
                                   int* __restrict__ deg_out, int* __restrict__ deg_in,
                                   unsigned* __restrict__ hist) {
    int e = blockIdx.x * 256 + threadIdx.x;
    if (e < NEDGE) {
        int src = ei[e], dst = ei[NEDGE + e];
        atomicAdd(&deg_out[src], 1);
        atomicAdd(&deg_in[dst], 1);
        atomicAdd(&hist[(src >> 6) * 2048 + dst], 1);
    }
}

// ---------------- 3-kernel coalesced parallel scan ----------------
__global__ void edge_scan1_kernel(const unsigned* __restrict__ hist,
                                  unsigned* __restrict__ offsets, unsigned* __restrict__ blocksum) {
    __shared__ unsigned tmp[256];
    int t = threadIdx.x;
    int g = blockIdx.x * 256 + t;
    unsigned v = hist[g];
    tmp[t] = v; __syncthreads();
    for (int off = 1; off < 256; off <<= 1) {
        unsigned u = (t >= off) ? tmp[t - off] : 0;
        __syncthreads();
        tmp[t] += u;
        __syncthreads();
    }
    offsets[g] = tmp[t] - v;
    if (t == 255) blocksum[blockIdx.x] = tmp[255];
}

__global__ void edge_scan2_kernel(unsigned* __restrict__ blocksum) {
    __shared__ unsigned tmp[256];
    int t = threadIdx.x;
    unsigned v = blocksum[t];
    tmp[t] = v; __syncthreads();
    for (int off = 1; off < 256; off <<= 1) {
        unsigned u = (t >= off) ? tmp[t - off] : 0;
        __syncthreads();
        tmp[t] += u;
        __syncthreads();
    }
    blocksum[t] = tmp[t] - v;
}

__global__ void edge_scan3_kernel(const unsigned* __restrict__ blocksum,
                                  unsigned* __restrict__ offsets, unsigned* __restrict__ cursor) {
    int g = blockIdx.x * 256 + threadIdx.x;
    unsigned o = offsets[g] + blocksum[blockIdx.x];
    offsets[g] = o; cursor[g] = o;
    if (g == 0) offsets[65536] = NEDGE;
}

__global__ void edge_scatter_kernel(const int* __restrict__ ei, const int* __restrict__ etypes,
                                    unsigned* __restrict__ cursor, unsigned* __restrict__ packed) {
    int e = blockIdx.x * 256 + threadIdx.x;
    if (e < NEDGE) {
        int src = ei[e], dst = ei[NEDGE + e];
        int key = (src >> 6) * 2048 + dst;
        unsigned pos = atomicAdd(&cursor[key], 1);
        packed[pos] = (unsigned)dst | ((unsigned)(src & 63) << 11) | ((unsigned)etypes[e] << 17);
    }
}

// ---------------- fused centrality + layernorm1 ----------------
__global__ void centrality_ln_kernel(float* __restrict__ h,
                                     const float* __restrict__ din_l,
                                     const float* __restrict__ dout_l,
                                     const int* __restrict__ deg_in,
                                     const int* __restrict__ deg_out,
                                     const float* __restrict__ g,
                                     const float* __restrict__ b,
                                     unsigned short* __restrict__ y) {
    int row = blockIdx.x;
    int tid = threadIdx.x;
    int di = min(max(deg_in[row], 0), MAXDEG);
    int dn = min(max(deg_out[row], 0), MAXDEG);
    float v = h[row * D_MODEL + tid] + din_l[di * D_MODEL + tid] + dout_l[dn * D_MODEL + tid];
    h[row * D_MODEL + tid] = v;
    __shared__ float red[256];
    red[tid] = v; __syncthreads();
    for (int s = 128; s > 0; s >>= 1) { if (tid < s) red[tid] += red[tid + s]; __syncthreads(); }
    float mu = red[0] * (1.0f / D_MODEL);
    __syncthreads();
    float d = v - mu;
    red[tid] = d * d; __syncthreads();
    for (int s = 128; s > 0; s >>= 1) { if (tid < s) red[tid] += red[tid + s]; __syncthreads(); }
    float rstd = rsqrtf(red[0] * (1.0f / D_MODEL) + 1e-5f);
    y[row * D_MODEL + tid] = f2bf(d * rstd * g[tid] + b[tid]);
}

// ---------------- layernorm2 ----------------
__global__ void layernorm_kernel(const float* __restrict__ x,
                                 const float* __restrict__ g,
                                 const float* __restrict__ b,
                                 unsigned short* __restrict__ y) {
    int row = blockIdx.x;
    int tid = threadIdx.x;
    float v = x[row * D_MODEL + tid];
    __shared__ float red[256];
    red[tid] = v; __syncthreads();
    for (int s = 128; s > 0; s >>= 1) { if (tid < s) red[tid] += red[tid + s]; __syncthreads(); }
    float mu = red[0] * (1.0f / D_MODEL);
    __syncthreads();
    float d = v - mu;
    red[tid] = d * d; __syncthreads();
    for (int s = 128; s > 0; s >>= 1) { if (tid < s) red[tid] += red[tid + s]; __syncthreads(); }
    float rstd = rsqrtf(red[0] * (1.0f / D_MODEL) + 1e-5f);
    y[row * D_MODEL + tid] = f2bf(d * rstd * g[tid] + b[tid]);
}

// ---------------- bf16 MFMA GEMM, 32x64 tile, prefetched K-loop ----------------
template <int ACT, bool RESID, bool OUTBF16, bool AFP32>
__global__ void gemm_mfma_kernel(const void* __restrict__ Av,
                                 const unsigned short* __restrict__ Wt,
                                 const float* __restrict__ bias,
                                 float* __restrict__ C, unsigned short* __restrict__ Cb,
                                 int Nc, int K) {
    __shared__ __align__(16) unsigned short As[32][72];
    __shared__ __align__(16) unsigned short Bs[64][72];
    const unsigned short* A16 = (const unsigned short*)Av;
    const float* A32 = (const float*)Av;
    int tid = threadIdx.x;
    int m0 = blockIdx.y * 32, n0 = blockIdx.x * 64;
    int w = tid >> 6, lane = tid & 63;
    int rg = (w & 1) * 16, cg = (w >> 1) * 32;
    int m = lane & 15, quad = lane >> 4;
    f32x4 acc[2] = {{0.f, 0.f, 0.f, 0.f}, {0.f, 0.f, 0.f, 0.f}};
    int ar = tid >> 3, ac = (tid & 7) * 8;
    uint4 ra; float4 fa0, fa1; uint4 rb0, rb1;
    if (AFP32) {
        fa0 = *(const float4*)&A32[(size_t)(m0 + ar) * K + ac];
        fa1 = *(const float4*)&A32[(size_t)(m0 + ar) * K + ac + 4];
    } else {
        ra = *(const uint4*)&A16[(size_t)(m0 + ar) * K + ac];
    }
    rb0 = *(const uint4*)&Wt[(size_t)(n0 + ar) * K + ac];
    rb1 = *(const uint4*)&Wt[(size_t)(n0 + 32 + ar) * K + ac];
    for (int k0 = 0; k0 < K; k0 += 64) {
        if (AFP32) {
            u16x4 t0 = {f2bf(fa0.x), f2bf(fa0.y), f2bf(fa0.z), f2bf(fa0.w)};
            u16x4 t1 = {f2bf(fa1.x), f2bf(fa1.y), f2bf(fa1.z), f2bf(fa1.w)};
            *(u16x4*)&As[ar][ac] = t0;
            *(u16x4*)&As[ar][ac + 4] = t1;
        } else {
            *(uint4*)&As[ar][ac] = ra;
        }
        *(uint4*)&Bs[ar][ac] = rb0;
        *(uint4*)&Bs[ar + 32][ac] = rb1;
        __syncthreads();
        int kn = k0 + 64;
        if (kn < K) {
            if (AFP32) {
                fa0 = *(const float4*)&A32[(size_t)(m0 + ar) * K + kn + ac];
                fa1 = *(const float4*)&A32[(size_t)(m0 + ar) * K + kn + ac + 4];
            } else {
                ra = *(const uint4*)&A16[(size_t)(m0 + ar) * K + kn + ac];
            }
            rb0 = *(const uint4*)&Wt[(size_t)(n0 + ar) * K + kn + ac];
            rb1 = *(const uint4*)&Wt[(size_t)(n0 + 32 + ar) * K + kn + ac];
        }
        #pragma unroll
        for (int ks = 0; ks < 2; ks++) {
            short8 a = *(const short8*)&As[rg + m][ks * 32 + quad * 8];
            #pragma unroll
            for (int t = 0; t < 2; t++) {
                short8 b = *(const short8*)&Bs[cg + t * 16 + m][ks * 32 + quad * 8];
                acc[t] = __builtin_amdgcn_mfma_f32_16x16x32_bf16(a, b, acc[t], 0, 0, 0);
            }
        }
        __syncthreads();
    }
    #pragma unroll
    for (int t = 0; t < 2; t++) {
        #pragma unroll
        for (int reg = 0; reg < 4; reg++) {
            int row = m0 + rg + quad * 4 + reg;
            int col = n0 + cg + t * 16 + m;
            float val = acc[t][reg] + bias[col];
            if (ACT == 1) val = val * 0.5f * (1.0f + erff(val * 0.7071067811865476f));
            size_t idx = (size_t)row * Nc + col;
            if (RESID) val += C[idx];
            if (OUTBF16) Cb[idx] = f2bf(val);
            else C[idx] = val;
        }
    }
}

// ---------------- bf16 MFMA GEMM, 64x64 tile, prefetched; optional v^T side-write ----------------
template <int ACT, bool VBT>
__global__ void gemm64_kernel(const unsigned short* __restrict__ A,
                              const unsigned short* __restrict__ Wt,
                              const float* __restrict__ bias,
                              unsigned short* __restrict__ Cb,
                              unsigned short* __restrict__ vbt,
                              int Nc, int K) {
    __shared__ __align__(16) unsigned short As[64][72];
    __shared__ __align__(16) unsigned short Bs[64][72];
    int tid = threadIdx.x;
    int m0 = blockIdx.y * 64, n0 = blockIdx.x * 64;
    int w = tid >> 6, lane = tid & 63;
    int wr = (w & 1) * 32, wc = (w >> 1) * 32;
    int m = lane & 15, quad = lane >> 4;
    f32x4 acc[2][2] = {{{0.f,0.f,0.f,0.f},{0.f,0.f,0.f,0.f}},{{0.f,0.f,0.f,0.f},{0.f,0.f,0.f,0.f}}};
    int sr = tid >> 2, sg = (tid & 3) * 16;
    uint4 a0 = *(const uint4*)&A[(size_t)(m0 + sr) * K + sg];
    uint4 a1 = *(const uint4*)&A[(size_t)(m0 + sr) * K + sg + 8];
    uint4 b0 = *(const uint4*)&Wt[(size_t)(n0 + sr) * K + sg];
    uint4 b1 = *(const uint4*)&Wt[(size_t)(n0 + sr) * K + sg + 8];
    for (int k0 = 0; k0 < K; k0 += 64) {
        *(uint4*)&As[sr][sg] = a0;
        *(uint4*)&As[sr][sg + 8] = a1;
        *(uint4*)&Bs[sr][sg] = b0;
        *(uint4*)&Bs[sr][sg + 8] = b1;
        __syncthreads();
        int kn = k0 + 64;
        if (kn < K) {
            a0 = *(const uint4*)&A[(size_t)(m0 + sr) * K + kn + sg];
            a1 = *(const uint4*)&A[(size_t)(m0 + sr) * K + kn + sg + 8];
            b0 = *(const uint4*)&Wt[(size_t)(n0 + sr) * K + kn + sg];
            b1 = *(const uint4*)&Wt[(size_t)(n0 + sr) * K + kn + sg + 8];
        }
        #pragma unroll
        for (int kh = 0; kh < 2; kh++) {
            short8 x0 = *(const short8*)&As[wr + m][kh * 32 + quad * 8];
            short8 x1 = *(const short8*)&As[wr + 16 + m][kh * 32 + quad * 8];
            short8 y0 = *(const short8*)&Bs[wc + m][kh * 32 + quad * 8];
            short8 y1 = *(const short8*)&Bs[wc + 16 + m][kh * 32 + quad * 8];
            acc[0][0] = __builtin_amdgcn_mfma_f32_16x16x32_bf16(x0, y0, acc[0][0], 0, 0, 0);
            acc[0][1] = __builtin_amdgcn_mfma_f32_16x16x32_bf16(x0, y1, acc[0][1], 0, 0, 0);
            acc[1][0] = __builtin_amdgcn_mfma_f32_16x16x32_bf16(x1, y0, acc[1][0], 0, 0, 0);
            acc[1][1] = __builtin_amdgcn_mfma_f32_16x16x32_bf16(x1, y1, acc[1][1], 0, 0, 0);
        }
        __syncthreads();
    }
    #pragma unroll
    for (int mt = 0; mt < 2; mt++) {
        #pragma unroll
        for (int nt = 0; nt < 2; nt++) {
            #pragma unroll
            for (int reg = 0; reg < 4; reg++) {
                int row = m0 + wr + mt * 16 + quad * 4 + reg;
                int col = n0 + wc + nt * 16 + m;
                float val = acc[mt][nt][reg] + bias[col];
                if (ACT == 1) val = val * 0.5f * (1.0f + erff(val * 0.7071067811865476f));
                unsigned short bv = f2bf(val);
                Cb[(size_t)row * Nc + col] = bv;
                if (VBT && col >= 512)
                    vbt[(size_t)(col - 512) * N_NODES + row] = bv;
            }
        }
    }
}

// ---------------- flash attention v5: K/V MFMA operands direct from global (L2-resident),
// LDS only for bias tile + P. JSPLIT=8. grid (N/64, H, JSPLIT), block 256 = 4 waves. ----------------
__global__ __launch_bounds__(256)
void flash_attn_kernel(const unsigned short* __restrict__ qkvb,
                       const unsigned short* __restrict__ vbt,
                       const unsigned char* __restrict__ bucket,
                       const float* __restrict__ spd_l,
                       const float* __restrict__ et_l,
                       const unsigned* __restrict__ offsets,
                       const unsigned* __restrict__ packed,
                       float* __restrict__ part_O,
                       float* __restrict__ m_part, float* __restrict__ l_part) {
    __shared__ __align__(16) float ov[64][68];   // bias tile; own-wave rows reused for float P
    __shared__ float et[8];

    int tid = threadIdx.x;
    int rb = blockIdx.x;
    int i0 = rb * 64;
    int hh = blockIdx.y;
    int js = blockIdx.z;
    int lane = tid & 63;
    if (tid < 8) et[tid] = et_l[tid * NHEAD + hh];
    float spd_reg = spd_l[(lane < 11 ? lane : 10) * NHEAD + hh];

    int w = tid >> 6;
    int m = lane & 15, quad = lane >> 4;
    int r0 = w * 16;
    short8 aq = *(const short8*)&qkvb[(size_t)(i0 + r0 + m) * 768 + hh * DH + quad * 8];
    float m_st[4], l_st[4];
    #pragma unroll
    for (int r = 0; r < 4; r++) { m_st[r] = -3.0e38f; l_st[r] = 0.f; }
    f32x4 oacc[2] = {{0.f, 0.f, 0.f, 0.f}, {0.f, 0.f, 0.f, 0.f}};
    const float scale = 0.17677669529663687f;

    int brow = tid >> 2, bcol = (tid & 3) * 16;

    for (int jt = 0; jt < N_NODES / JSPLIT / 64; jt++) {
        int j0 = js * (N_NODES / JSPLIT) + jt * 64;
        __syncthreads();   // previous iteration's P reads / bias reads done
        // K fragments direct from global (perfectly coalesced: 16 rows x 64 B per instr, L2-hit)
        short8 bk8[4];
        #pragma unroll
        for (int t = 0; t < 4; t++)
            bk8[t] = *(const short8*)&qkvb[(size_t)(j0 + t * 16 + m) * 768 + 256 + hh * DH + quad * 8];
        {   // bias tile: spd gather via ds_bpermute on the register LUT, vectorized store
            uint4 b16 = *(const uint4*)&bucket[(size_t)(i0 + brow) * N_NODES + j0 + bcol];
            const unsigned char* bb = (const unsigned char*)&b16;
            float fb[16];
            #pragma unroll
            for (int i = 0; i < 16; i++)
                fb[i] = __int_as_float(
                    __builtin_amdgcn_ds_bpermute(((int)bb[i]) << 2, __float_as_int(spd_reg)));
            #pragma unroll
            for (int g = 0; g < 4; g++) {
                f32x4 st = {fb[g * 4], fb[g * 4 + 1], fb[g * 4 + 2], fb[g * 4 + 3]};
                *(f32x4*)&ov[brow][bcol + g * 4] = st;
            }
        }
        __syncthreads();   // bias tile initialized
        {   // sparse edge bias
            unsigned key0 = (unsigned)rb * 2048 + j0;
            unsigned start = offsets[key0], end = offsets[key0 + 64];
            for (unsigned i = start + tid; i < end; i += 256) {
                unsigned p = packed[i];
                atomicAdd(&ov[(p >> 11) & 63][(p & 2047) - j0], et[(p >> 17) & 7]);
            }
        }
        __syncthreads();   // edges applied
        // S = QK^T*scale + bias (C-layout registers)
        float sv[4][4];
        #pragma unroll
        for (int t = 0; t < 4; t++) {
            f32x4 z = {0.f, 0.f, 0.f, 0.f};
            f32x4 sacc = __builtin_amdgcn_mfma_f32_16x16x32_bf16(aq, bk8[t], z, 0, 0, 0);
            #pragma unroll
            for (int r = 0; r < 4; r++)
                sv[t][r] = sacc[r] * scale + ov[r0 + quad * 4 + r][t * 16 + m];
        }
        // V fragments direct from global; softmax VALU work below hides the L2 latency
        short8 vb[2][2];
        #pragma unroll
        for (int t = 0; t < 2; t++)
            #pragma unroll
            for (int kh = 0; kh < 2; kh++)
                vb[t][kh] = *(const short8*)&vbt[(size_t)(hh * DH + t * 16 + m) * N_NODES +
                                                 j0 + kh * 32 + quad * 8];
        // online softmax: 16-lane row reductions via DPP rotates (VALU pipe)
        float alpha[4];
        #pragma unroll
        for (int r = 0; r < 4; r++) {
            float mx = fmaxf(fmaxf(sv[0][r], sv[1][r]), fmaxf(sv[2][r], sv[3][r]));
            mx = fmaxf(mx, dpp_ror<0x121>(mx));
            mx = fmaxf(mx, dpp_ror<0x122>(mx));
            mx = fmaxf(mx, dpp_ror<0x124>(mx));
            mx = fmaxf(mx, dpp_ror<0x128>(mx));
            float mn = fmaxf(m_st[r], mx);
            alpha[r] = __expf(m_st[r] - mn);
            m_st[r] = mn;
            float ps = 0.f;
            #pragma unroll
            for (int t = 0; t < 4; t++) { float pv = __expf(sv[t][r] - mn); sv[t][r] = pv; ps += pv; }
            ps += dpp_ror<0x121>(ps);
            ps += dpp_ror<0x122>(ps);
            ps += dpp_ror<0x124>(ps);
            ps += dpp_ror<0x128>(ps);
            l_st[r] = l_st[r] * alpha[r] + ps;
        }
        // float P into own wave's rows of ov (C-layout write, 2-way banks)
        #pragma unroll
        for (int t = 0; t < 4; t++)
            #pragma unroll
            for (int r = 0; r < 4; r++)
                ov[r0 + quad * 4 + r][t * 16 + m] = sv[t][r];
        #pragma unroll
        for (int r = 0; r < 4; r++) { oacc[0][r] *= alpha[r]; oacc[1][r] *= alpha[r]; }
        __builtin_amdgcn_s_waitcnt(0xC07F);   // lgkmcnt(0): own-wave P writes visible
        #pragma unroll
        for (int kh = 0; kh < 2; kh++) {
            f32x4 p0 = *(const f32x4*)&ov[r0 + m][kh * 32 + quad * 8];
            f32x4 p1 = *(const f32x4*)&ov[r0 + m][kh * 32 + quad * 8 + 4];
            short8 pa;
            pa[0] = (short)f2bf(p0[0]); pa[1] = (short)f2bf(p0[1]);
            pa[2] = (short)f2bf(p0[2]); pa[3] = (short)f2bf(p0[3]);
            pa[4] = (short)f2bf(p1[0]); pa[5] = (short)f2bf(p1[1]);
            pa[6] = (short)f2bf(p1[2]); pa[7] = (short)f2bf(p1[3]);
            #pragma unroll
            for (int t = 0; t < 2; t++)
                oacc[t] = __builtin_amdgcn_mfma_f32_16x16x32_bf16(pa, vb[t][kh], oacc[t], 0, 0, 0);
        }
    }
    #pragma unroll
    for (int t = 0; t < 2; t++)
        #pragma unroll
        for (int r = 0; r < 4; r++)
            part_O[((size_t)js * N_NODES + i0 + r0 + quad * 4 + r) * D_MODEL + hh * DH + t * 16 + m] =
                oacc[t][r];
    if (m == 0) {
        #pragma unroll
        for (int r = 0; r < 4; r++) {
            int row = i0 + r0 + quad * 4 + r;
            m_part[((size_t)js * NHEAD + hh) * N_NODES + row] = m_st[r];
            l_part[((size_t)js * NHEAD + hh) * N_NODES + row] = l_st[r];
        }
    }
}

// ---------------- merge j-split partials -> bf16 attn out ----------------
__global__ void flash_merge_kernel(const float* __restrict__ part_O,
                                   const float* __restrict__ m_part,
                                   const float* __restrict__ l_part,
                                   unsigned short* __restrict__ aoutb) {
    int e = blockIdx.x * 256 + threadIdx.x;
    int row = e >> 8, col = e & 255, h = col >> 5;
    float mv[JSPLIT];
    float mg = -3.0e38f;
    #pragma unroll
    for (int js = 0; js < JSPLIT; js++) {
        mv[js] = m_part[((size_t)js * NHEAD + h) * N_NODES + row];
        mg = fmaxf(mg, mv[js]);
    }
    float o = 0.f, l = 0.f;
    #pragma unroll
    for (int js = 0; js < JSPLIT; js++) {
        float sc = __expf(mv[js] - mg);
        o += sc * part_O[(size_t)js * N_NODES * D_MODEL + e];
        l += sc * l_part[((size_t)js * NHEAD + h) * N_NODES + row];
    }
    aoutb[e] = f2bf(o / l);
}

// 256-byte-aligned workspace allocation
#define WS_ALLOC(type, name, count) \
    type* name = (type*)base; base += (((size_t)(count) * sizeof(type)) + 255) & ~(size_t)255;

extern "C" void kernel_launch(void* const* d_in, const int* in_sizes, int n_in,
                              void* d_out, int out_size, void* d_ws, size_t ws_size,
                              hipStream_t stream) {
    const float* x          = (const float*)d_in[0];
    const int*   edge_index = (const int*)d_in[1];
    const int*   edge_types = (const int*)d_in[2];
    const float* pos        = (const float*)d_in[3];
    const float* W_emb      = (const float*)d_in[4];
    const float* b_emb      = (const float*)d_in[5];
    const float* Wq         = (const float*)d_in[6];
    const float* Wk         = (const float*)d_in[7];
    const float* Wv         = (const float*)d_in[8];
    const float* Wo         = (const float*)d_in[9];
    const float* bq         = (const float*)d_in[10];
    const float* bk         = (const float*)d_in[11];
    const float* bv         = (const float*)d_in[12];
    const float* bo         = (const float*)d_in[13];
    const float* spd_table  = (const float*)d_in[14];
    const float* edge_table = (const float*)d_in[15];
    const float* din_emb    = (const float*)d_in[16];
    const float* dout_emb   = (const float*)d_in[17];
    const float* ln1_g      = (const float*)d_in[18];
    const float* ln1_b      = (const float*)d_in[19];
    const float* ln2_g      = (const float*)d_in[20];
    const float* ln2_b      = (const float*)d_in[21];
    const float* W1         = (const float*)d_in[22];
    const float* b1         = (const float*)d_in[23];
    const float* W2         = (const float*)d_in[24];
    const float* b2         = (const float*)d_in[25];
    const float* W_out      = (const float*)d_in[26];
    const float* b_out      = (const float*)d_in[27];
    float* out = (float*)d_out;

    char* base = (char*)d_ws;
    WS_ALLOC(int, deg_out, N_NODES)
    WS_ALLOC(int, deg_in, N_NODES)
    WS_ALLOC(float, h, N_NODES * D_MODEL)
    WS_ALLOC(unsigned short, xb, N_NODES * D_MODEL)
    WS_ALLOC(unsigned short, qkvb, N_NODES * 768)
    WS_ALLOC(unsigned short, vbt, D_MODEL * N_NODES)
    WS_ALLOC(unsigned short, aoutb, N_NODES * D_MODEL)
    WS_ALLOC(unsigned short, ffnb, N_NODES * D_FF)
    WS_ALLOC(unsigned char, bucket, (size_t)N_NODES * N_NODES)
    WS_ALLOC(unsigned short, qkvt, NLAYER * 768 * D_MODEL)
    WS_ALLOC(unsigned short, wot, NLAYER * D_MODEL * D_MODEL)
    WS_ALLOC(unsigned short, w1t, NLAYER * D_MODEL * D_FF)
    WS_ALLOC(unsigned short, w2t, NLAYER * D_FF * D_MODEL)
    WS_ALLOC(unsigned short, wembt, D_FEAT * D_MODEL)
    WS_ALLOC(unsigned short, woutt, D_MODEL * D_OUT)
    WS_ALLOC(float, bqkv, NLAYER * 768)
    WS_ALLOC(unsigned, hist, 65536)
    WS_ALLOC(unsigned, offsets, 65537)
    WS_ALLOC(unsigned, cursor, 65536)
    WS_ALLOC(unsigned, blocksum, 256)
    WS_ALLOC(unsigned, packed, NEDGE)
    WS_ALLOC(float, part_O, (size_t)JSPLIT * N_NODES * D_MODEL)
    WS_ALLOC(float, m_part, (size_t)JSPLIT * NHEAD * N_NODES)
    WS_ALLOC(float, l_part, (size_t)JSPLIT * NHEAD * N_NODES)

    // ---- prep ----
    mega_prep_kernel<<<5702, 256, 0, stream>>>(pos, bucket, hist, deg_out, deg_in,
                                               Wq, Wk, Wv, Wo, W1, W2, W_emb, W_out,
                                               bq, bk, bv, qkvt, wot, w1t, w2t, wembt, woutt, bqkv);
    degree_hist_kernel<<<NEDGE / 256, 256, 0, stream>>>(edge_index, deg_out, deg_in, hist);
    edge_scan1_kernel<<<256, 256, 0, stream>>>(hist, offsets, blocksum);
    edge_scan2_kernel<<<1, 256, 0, stream>>>(blocksum);
    edge_scan3_kernel<<<256, 256, 0, stream>>>(blocksum, offsets, cursor);
    edge_scatter_kernel<<<NEDGE / 256, 256, 0, stream>>>(edge_index, edge_types, cursor, packed);

    // embed: h = x @ W_emb + b_emb (fp32 A, cast in staging)
    gemm_mfma_kernel<0, false, false, true><<<dim3(D_MODEL / 64, N_NODES / 32), 256, 0, stream>>>(
        x, wembt, b_emb, h, nullptr, D_MODEL, D_FEAT);

    for (int l = 0; l < NLAYER; l++) {
        centrality_ln_kernel<<<N_NODES, 256, 0, stream>>>(
            h, din_emb + (size_t)l * (MAXDEG + 1) * D_MODEL,
            dout_emb + (size_t)l * (MAXDEG + 1) * D_MODEL, deg_in, deg_out,
            ln1_g + l * D_MODEL, ln1_b + l * D_MODEL, xb);

        gemm64_kernel<0, true><<<dim3(768 / 64, N_NODES / 64), 256, 0, stream>>>(
            xb, qkvt + (size_t)l * 768 * D_MODEL, bqkv + l * 768, qkvb, vbt, 768, D_MODEL);

        flash_attn_kernel<<<dim3(N_NODES / 64, NHEAD, JSPLIT), 256, 0, stream>>>(
            qkvb, vbt, bucket, spd_table + (size_t)l * 11 * NHEAD,
            edge_table + (size_t)l * 8 * NHEAD, offsets, packed, part_O, m_part, l_part);

        flash_merge_kernel<<<N_NODES * D_MODEL / 256, 256, 0, stream>>>(part_O, m_part, l_part, aoutb);

        // O-proj: h += aout @ Wo + bo
        gemm_mfma_kernel<0, true, false, false><<<dim3(D_MODEL / 64, N_NODES / 32), 256, 0, stream>>>(
            aoutb, wot + (size_t)l * D_MODEL * D_MODEL, bo + l * D_MODEL, h, nullptr, D_MODEL, D_MODEL);

        layernorm_kernel<<<N_NODES, 256, 0, stream>>>(h, ln2_g + l * D_MODEL, ln2_b + l * D_MODEL, xb);

        gemm64_kernel<1, false><<<dim3(D_FF / 64, N_NODES / 64), 256, 0, stream>>>(
            xb, w1t + (size_t)l * D_MODEL * D_FF, b1 + l * D_FF, ffnb, nullptr, D_FF, D_MODEL);

        gemm_mfma_kernel<0, true, false, false><<<dim3(D_MODEL / 64, N_NODES / 32), 256, 0, stream>>>(
            ffnb, w2t + (size_t)l * D_FF * D_MODEL, b2 + l * D_MODEL, h, nullptr, D_MODEL, D_FF);
    }

    // final: out = h @ W_out + b_out (fp32 A, cast in staging)
    gemm_mfma_kernel<0, false, false, true><<<dim3(D_OUT / 64, N_NODES / 32), 256, 0, stream>>>(
        h, woutt, b_out, out, nullptr, D_OUT, D_MODEL);
}

// Round 13
// 316.562 us; speedup vs baseline: 1.0215x; 1.0215x over previous
//
#include <hip/hip_runtime.h>
#include <math.h>

#define N_NODES 2048
#define D_MODEL 256
#define D_FEAT 128
#define NHEAD 8
#define DH 32
#define NLAYER 2
#define NEDGE 65536
#define D_FF 1024
#define D_OUT 128
#define MAXDEG 512
#define JSPLIT 4

typedef __attribute__((ext_vector_type(8))) short short8;
typedef __attribute__((ext_vector_type(4))) float f32x4;
typedef __attribute__((ext_vector_type(4))) unsigned short u16x4;

__device__ __forceinline__ unsigned short f2bf(float f) {
    unsigned u = __float_as_uint(f);
    unsigned r = (u + 0x7FFFu + ((u >> 16) & 1u)) >> 16;
    return (unsigned short)r;
}

template <int CTRL>
__device__ __forceinline__ float dpp_ror(float x) {
    return __int_as_float(__builtin_amdgcn_update_dpp(0, __float_as_int(x), CTRL, 0xf, 0xf, false));
}

// ---------------- mega prep: bucket table + zeroing + all weight transposes ----------------
__device__ __forceinline__ void wt_tile(const float* __restrict__ W, unsigned short* __restrict__ Wt,
                                        int K, int Nc, int n0, int k0, int tid,
                                        unsigned short (*tile)[33]) {
    int r = tid >> 3, cg = (tid & 7) * 4;
    float4 w4 = *(const float4*)&W[(size_t)(k0 + r) * Nc + n0 + cg];
    tile[r][cg + 0] = f2bf(w4.x); tile[r][cg + 1] = f2bf(w4.y);
    tile[r][cg + 2] = f2bf(w4.z); tile[r][cg + 3] = f2bf(w4.w);
    __syncthreads();
    int c = tid >> 3, rg = (tid & 7) * 4;
    u16x4 o;
    #pragma unroll
    for (int j = 0; j < 4; j++) o[j] = tile[rg + j][c];
    *(u16x4*)&Wt[(size_t)(n0 + c) * K + k0 + rg] = o;
}

__global__ void mega_prep_kernel(const float* __restrict__ pos, unsigned char* __restrict__ bucket,
                                 unsigned* __restrict__ hist, int* __restrict__ deg_out,
                                 int* __restrict__ deg_in,
                                 const float* __restrict__ Wq, const float* __restrict__ Wk,
                                 const float* __restrict__ Wv, const float* __restrict__ Wo,
                                 const float* __restrict__ W1, const float* __restrict__ W2,
                                 const float* __restrict__ W_emb, const float* __restrict__ W_out,
                                 const float* __restrict__ bq, const float* __restrict__ bk,
                                 const float* __restrict__ bv,
                                 unsigned short* __restrict__ qkvt, unsigned short* __restrict__ wot,
                                 unsigned short* __restrict__ w1t, unsigned short* __restrict__ w2t,
                                 unsigned short* __restrict__ wembt, unsigned short* __restrict__ woutt,
                                 float* __restrict__ bqkv) {
    __shared__ unsigned short tile[32][33];
    int b = blockIdx.x, tid = threadIdx.x;
    if (b < 4096) {                      // bucket table (N*N/4 u32 elements over 4096 blocks)
        int i = b * 256 + tid;
        float4 p = *(const float4*)&pos[(size_t)i * 4];
        unsigned b0 = (unsigned)fminf(fmaxf(p.x * 10.f + 0.5f, 0.f), 10.f);
        unsigned b1 = (unsigned)fminf(fmaxf(p.y * 10.f + 0.5f, 0.f), 10.f);
        unsigned b2 = (unsigned)fminf(fmaxf(p.z * 10.f + 0.5f, 0.f), 10.f);
        unsigned b3 = (unsigned)fminf(fmaxf(p.w * 10.f + 0.5f, 0.f), 10.f);
        ((unsigned*)bucket)[i] = b0 | (b1 << 8) | (b2 << 16) | (b3 << 24);
        if (b < 64) {
            #pragma unroll
            for (int k = 0; k < 4; k++) hist[b * 1024 + k * 256 + tid] = 0;
        } else if (b == 64) {
            #pragma unroll
            for (int k = 0; k < 8; k++) deg_out[k * 256 + tid] = 0;
            #pragma unroll
            for (int k = 0; k < 8; k++) deg_in[k * 256 + tid] = 0;
        }
        return;
    }
    int bb = b - 4096;
    if (bb < 512) {
        int z = bb >> 6, t = bb & 63;
        int l = z >> 2, which = z & 3;
        const float* W = (which == 0 ? Wq : which == 1 ? Wk : which == 2 ? Wv : Wo) + (size_t)l * 65536;
        unsigned short* dst = (which < 3) ? qkvt + (size_t)l * 196608 + which * 65536
                                          : wot + (size_t)l * 65536;
        wt_tile(W, dst, 256, 256, (t & 7) * 32, (t >> 3) * 32, tid, tile);
    } else if (bb < 1024) {
        int b2 = bb - 512, l = b2 >> 8, t = b2 & 255;
        wt_tile(W1 + (size_t)l * D_MODEL * D_FF, w1t + (size_t)l * D_MODEL * D_FF,
                D_MODEL, D_FF, (t & 31) * 32, (t >> 5) * 32, tid, tile);
    } else if (bb < 1536) {
        int b3 = bb - 1024, l = b3 >> 8, t = b3 & 255;
        wt_tile(W2 + (size_t)l * D_FF * D_MODEL, w2t + (size_t)l * D_FF * D_MODEL,
                D_FF, D_MODEL, (t & 7) * 32, (t >> 3) * 32, tid, tile);
    } else if (bb < 1568) {
        int b4 = bb - 1536;
        wt_tile(W_emb, wembt, D_FEAT, D_MODEL, (b4 & 7) * 32, (b4 >> 3) * 32, tid, tile);
    } else if (bb < 1600) {
        int b5 = bb - 1568;
        wt_tile(W_out, woutt, D_MODEL, D_OUT, (b5 & 3) * 32, (b5 >> 2) * 32, tid, tile);
    } else {
        int i = (bb - 1600) * 256 + tid;
        if (i < NLAYER * 768) {
            int l = i / 768, j = i % 768;
            const float* src = j < 256 ? bq : j < 512 ? bk : bv;
            bqkv[i] = src[l * 256 + (j & 255)];
        }
    }
}

// ---------------- degree + edge histogram ----------------
__global__ void degree_hist_kernel(const int* __restrict__ ei,
                                   int* __restrict__ deg_out, int* __restrict__ deg_in,
                                   unsigned* __restrict__ hist) {
    int e = blockIdx.x * 256 + threadIdx.x;
    if (e < NEDGE) {
        int src = ei[e], dst = ei[NEDGE + e];
        atomicAdd(&deg_out[src], 1);
        atomicAdd(&deg_in[dst], 1);
        atomicAdd(&hist[(src >> 6) * 2048 + dst], 1);
    }
}

// ---------------- 3-kernel coalesced parallel scan ----------------
__global__ void edge_scan1_kernel(const unsigned* __restrict__ hist,
                                  unsigned* __restrict__ offsets, unsigned* __restrict__ blocksum) {
    __shared__ unsigned tmp[256];
    int t = threadIdx.x;
    int g = blockIdx.x * 256 + t;
    unsigned v = hist[g];
    tmp[t] = v; __syncthreads();
    for (int off = 1; off < 256; off <<= 1) {
        unsigned u = (t >= off) ? tmp[t - off] : 0;
        __syncthreads();
        tmp[t] += u;
        __syncthreads();
    }
    offsets[g] = tmp[t] - v;
    if (t == 255) blocksum[blockIdx.x] = tmp[255];
}

__global__ void edge_scan2_kernel(unsigned* __restrict__ blocksum) {
    __shared__ unsigned tmp[256];
    int t = threadIdx.x;
    unsigned v = blocksum[t];
    tmp[t] = v; __syncthreads();
    for (int off = 1; off < 256; off <<= 1) {
        unsigned u = (t >= off) ? tmp[t - off] : 0;
        __syncthreads();
        tmp[t] += u;
        __syncthreads();
    }
    blocksum[t] = tmp[t] - v;
}

__global__ void edge_scan3_kernel(const unsigned* __restrict__ blocksum,
                                  unsigned* __restrict__ offsets, unsigned* __restrict__ cursor) {
    int g = blockIdx.x * 256 + threadIdx.x;
    unsigned o = offsets[g] + blocksum[blockIdx.x];
    offsets[g] = o; cursor[g] = o;
    if (g == 0) offsets[65536] = NEDGE;
}

__global__ void edge_scatter_kernel(const int* __restrict__ ei, const int* __restrict__ etypes,
                                    unsigned* __restrict__ cursor, unsigned* __restrict__ packed) {
    int e = blockIdx.x * 256 + threadIdx.x;
    if (e < NEDGE) {
        int src = ei[e], dst = ei[NEDGE + e];
        int key = (src >> 6) * 2048 + dst;
        unsigned pos = atomicAdd(&cursor[key], 1);
        packed[pos] = (unsigned)dst | ((unsigned)(src & 63) << 11) | ((unsigned)etypes[e] << 17);
    }
}

// ---------------- fused centrality + layernorm1 ----------------
__global__ void centrality_ln_kernel(float* __restrict__ h,
                                     const float* __restrict__ din_l,
                                     const float* __restrict__ dout_l,
                                     const int* __restrict__ deg_in,
                                     const int* __restrict__ deg_out,
                                     const float* __restrict__ g,
                                     const float* __restrict__ b,
                                     unsigned short* __restrict__ y) {
    int row = blockIdx.x;
    int tid = threadIdx.x;
    int di = min(max(deg_in[row], 0), MAXDEG);
    int dn = min(max(deg_out[row], 0), MAXDEG);
    float v = h[row * D_MODEL + tid] + din_l[di * D_MODEL + tid] + dout_l[dn * D_MODEL + tid];
    h[row * D_MODEL + tid] = v;
    __shared__ float red[256];
    red[tid] = v; __syncthreads();
    for (int s = 128; s > 0; s >>= 1) { if (tid < s) red[tid] += red[tid + s]; __syncthreads(); }
    float mu = red[0] * (1.0f / D_MODEL);
    __syncthreads();
    float d = v - mu;
    red[tid] = d * d; __syncthreads();
    for (int s = 128; s > 0; s >>= 1) { if (tid < s) red[tid] += red[tid + s]; __syncthreads(); }
    float rstd = rsqrtf(red[0] * (1.0f / D_MODEL) + 1e-5f);
    y[row * D_MODEL + tid] = f2bf(d * rstd * g[tid] + b[tid]);
}

// ---------------- layernorm2 ----------------
__global__ void layernorm_kernel(const float* __restrict__ x,
                                 const float* __restrict__ g,
                                 const float* __restrict__ b,
                                 unsigned short* __restrict__ y) {
    int row = blockIdx.x;
    int tid = threadIdx.x;
    float v = x[row * D_MODEL + tid];
    __shared__ float red[256];
    red[tid] = v; __syncthreads();
    for (int s = 128; s > 0; s >>= 1) { if (tid < s) red[tid] += red[tid + s]; __syncthreads(); }
    float mu = red[0] * (1.0f / D_MODEL);
    __syncthreads();
    float d = v - mu;
    red[tid] = d * d; __syncthreads();
    for (int s = 128; s > 0; s >>= 1) { if (tid < s) red[tid] += red[tid + s]; __syncthreads(); }
    float rstd = rsqrtf(red[0] * (1.0f / D_MODEL) + 1e-5f);
    y[row * D_MODEL + tid] = f2bf(d * rstd * g[tid] + b[tid]);
}

// ---------------- bf16 MFMA GEMM, 32x64 tile, prefetched K-loop ----------------
template <int ACT, bool RESID, bool OUTBF16, bool AFP32>
__global__ void gemm_mfma_kernel(const void* __restrict__ Av,
                                 const unsigned short* __restrict__ Wt,
                                 const float* __restrict__ bias,
                                 float* __restrict__ C, unsigned short* __restrict__ Cb,
                                 int Nc, int K) {
    __shared__ __align__(16) unsigned short As[32][72];
    __shared__ __align__(16) unsigned short Bs[64][72];
    const unsigned short* A16 = (const unsigned short*)Av;
    const float* A32 = (const float*)Av;
    int tid = threadIdx.x;
    int m0 = blockIdx.y * 32, n0 = blockIdx.x * 64;
    int w = tid >> 6, lane = tid & 63;
    int rg = (w & 1) * 16, cg = (w >> 1) * 32;
    int m = lane & 15, quad = lane >> 4;
    f32x4 acc[2] = {{0.f, 0.f, 0.f, 0.f}, {0.f, 0.f, 0.f, 0.f}};
    int ar = tid >> 3, ac = (tid & 7) * 8;
    uint4 ra; float4 fa0, fa1; uint4 rb0, rb1;
    if (AFP32) {
        fa0 = *(const float4*)&A32[(size_t)(m0 + ar) * K + ac];
        fa1 = *(const float4*)&A32[(size_t)(m0 + ar) * K + ac + 4];
    } else {
        ra = *(const uint4*)&A16[(size_t)(m0 + ar) * K + ac];
    }
    rb0 = *(const uint4*)&Wt[(size_t)(n0 + ar) * K + ac];
    rb1 = *(const uint4*)&Wt[(size_t)(n0 + 32 + ar) * K + ac];
    for (int k0 = 0; k0 < K; k0 += 64) {
        if (AFP32) {
            u16x4 t0 = {f2bf(fa0.x), f2bf(fa0.y), f2bf(fa0.z), f2bf(fa0.w)};
            u16x4 t1 = {f2bf(fa1.x), f2bf(fa1.y), f2bf(fa1.z), f2bf(fa1.w)};
            *(u16x4*)&As[ar][ac] = t0;
            *(u16x4*)&As[ar][ac + 4] = t1;
        } else {
            *(uint4*)&As[ar][ac] = ra;
        }
        *(uint4*)&Bs[ar][ac] = rb0;
        *(uint4*)&Bs[ar + 32][ac] = rb1;
        __syncthreads();
        int kn = k0 + 64;
        if (kn < K) {
            if (AFP32) {
                fa0 = *(const float4*)&A32[(size_t)(m0 + ar) * K + kn + ac];
                fa1 = *(const float4*)&A32[(size_t)(m0 + ar) * K + kn + ac + 4];
            } else {
                ra = *(const uint4*)&A16[(size_t)(m0 + ar) * K + kn + ac];
            }
            rb0 = *(const uint4*)&Wt[(size_t)(n0 + ar) * K + kn + ac];
            rb1 = *(const uint4*)&Wt[(size_t)(n0 + 32 + ar) * K + kn + ac];
        }
        #pragma unroll
        for (int ks = 0; ks < 2; ks++) {
            short8 a = *(const short8*)&As[rg + m][ks * 32 + quad * 8];
            #pragma unroll
            for (int t = 0; t < 2; t++) {
                short8 b = *(const short8*)&Bs[cg + t * 16 + m][ks * 32 + quad * 8];
                acc[t] = __builtin_amdgcn_mfma_f32_16x16x32_bf16(a, b, acc[t], 0, 0, 0);
            }
        }
        __syncthreads();
    }
    #pragma unroll
    for (int t = 0; t < 2; t++) {
        #pragma unroll
        for (int reg = 0; reg < 4; reg++) {
            int row = m0 + rg + quad * 4 + reg;
            int col = n0 + cg + t * 16 + m;
            float val = acc[t][reg] + bias[col];
            if (ACT == 1) val = val * 0.5f * (1.0f + erff(val * 0.7071067811865476f));
            size_t idx = (size_t)row * Nc + col;
            if (RESID) val += C[idx];
            if (OUTBF16) Cb[idx] = f2bf(val);
            else C[idx] = val;
        }
    }
}

// ---------------- bf16 MFMA GEMM, 64x64 tile, prefetched; optional v^T side-write ----------------
template <int ACT, bool VBT>
__global__ void gemm64_kernel(const unsigned short* __restrict__ A,
                              const unsigned short* __restrict__ Wt,
                              const float* __restrict__ bias,
                              unsigned short* __restrict__ Cb,
                              unsigned short* __restrict__ vbt,
                              int Nc, int K) {
    __shared__ __align__(16) unsigned short As[64][72];
    __shared__ __align__(16) unsigned short Bs[64][72];
    int tid = threadIdx.x;
    int m0 = blockIdx.y * 64, n0 = blockIdx.x * 64;
    int w = tid >> 6, lane = tid & 63;
    int wr = (w & 1) * 32, wc = (w >> 1) * 32;
    int m = lane & 15, quad = lane >> 4;
    f32x4 acc[2][2] = {{{0.f,0.f,0.f,0.f},{0.f,0.f,0.f,0.f}},{{0.f,0.f,0.f,0.f},{0.f,0.f,0.f,0.f}}};
    int sr = tid >> 2, sg = (tid & 3) * 16;
    uint4 a0 = *(const uint4*)&A[(size_t)(m0 + sr) * K + sg];
    uint4 a1 = *(const uint4*)&A[(size_t)(m0 + sr) * K + sg + 8];
    uint4 b0 = *(const uint4*)&Wt[(size_t)(n0 + sr) * K + sg];
    uint4 b1 = *(const uint4*)&Wt[(size_t)(n0 + sr) * K + sg + 8];
    for (int k0 = 0; k0 < K; k0 += 64) {
        *(uint4*)&As[sr][sg] = a0;
        *(uint4*)&As[sr][sg + 8] = a1;
        *(uint4*)&Bs[sr][sg] = b0;
        *(uint4*)&Bs[sr][sg + 8] = b1;
        __syncthreads();
        int kn = k0 + 64;
        if (kn < K) {
            a0 = *(const uint4*)&A[(size_t)(m0 + sr) * K + kn + sg];
            a1 = *(const uint4*)&A[(size_t)(m0 + sr) * K + kn + sg + 8];
            b0 = *(const uint4*)&Wt[(size_t)(n0 + sr) * K + kn + sg];
            b1 = *(const uint4*)&Wt[(size_t)(n0 + sr) * K + kn + sg + 8];
        }
        #pragma unroll
        for (int kh = 0; kh < 2; kh++) {
            short8 x0 = *(const short8*)&As[wr + m][kh * 32 + quad * 8];
            short8 x1 = *(const short8*)&As[wr + 16 + m][kh * 32 + quad * 8];
            short8 y0 = *(const short8*)&Bs[wc + m][kh * 32 + quad * 8];
            short8 y1 = *(const short8*)&Bs[wc + 16 + m][kh * 32 + quad * 8];
            acc[0][0] = __builtin_amdgcn_mfma_f32_16x16x32_bf16(x0, y0, acc[0][0], 0, 0, 0);
            acc[0][1] = __builtin_amdgcn_mfma_f32_16x16x32_bf16(x0, y1, acc[0][1], 0, 0, 0);
            acc[1][0] = __builtin_amdgcn_mfma_f32_16x16x32_bf16(x1, y0, acc[1][0], 0, 0, 0);
            acc[1][1] = __builtin_amdgcn_mfma_f32_16x16x32_bf16(x1, y1, acc[1][1], 0, 0, 0);
        }
        __syncthreads();
    }
    #pragma unroll
    for (int mt = 0; mt < 2; mt++) {
        #pragma unroll
        for (int nt = 0; nt < 2; nt++) {
            #pragma unroll
            for (int reg = 0; reg < 4; reg++) {
                int row = m0 + wr + mt * 16 + quad * 4 + reg;
                int col = n0 + wc + nt * 16 + m;
                float val = acc[mt][nt][reg] + bias[col];
                if (ACT == 1) val = val * 0.5f * (1.0f + erff(val * 0.7071067811865476f));
                unsigned short bv = f2bf(val);
                Cb[(size_t)row * Nc + col] = bv;
                if (VBT && col >= 512)
                    vbt[(size_t)(col - 512) * N_NODES + row] = bv;
            }
        }
    }
}

// ---------------- flash attention v6: wave-private bias quadrant, ZERO barriers in j-loop.
// K/V direct from global (L2); spd + edge-type gathers via bpermute on register LUTs.
// grid (N/64, H, JSPLIT), block 256 = 4 waves; wave w owns rows w*16..+16. ----------------
__global__ __launch_bounds__(256)
void flash_attn_kernel(const unsigned short* __restrict__ qkvb,
                       const unsigned short* __restrict__ vbt,
                       const unsigned char* __restrict__ bucket,
                       const float* __restrict__ spd_l,
                       const float* __restrict__ et_l,
                       const unsigned* __restrict__ offsets,
                       const unsigned* __restrict__ packed,
                       float* __restrict__ part_O,
                       float* __restrict__ m_part, float* __restrict__ l_part) {
    __shared__ __align__(16) float ov[64][68];   // per-wave-private quadrants (rows w*16..+16)

    int tid = threadIdx.x;
    int rb = blockIdx.x;
    int i0 = rb * 64;
    int hh = blockIdx.y;
    int js = blockIdx.z;
    int lane = tid & 63;
    // register LUTs, gathered per-wave via ds_bpermute (no LDS tables, no init barrier)
    float spd_reg = spd_l[(lane < 11 ? lane : 10) * NHEAD + hh];
    float et_reg  = et_l[((lane & 7)) * NHEAD + hh];    // lanes 0..7 pattern repeats; index <8 used

    int w = tid >> 6;
    int m = lane & 15, quad = lane >> 4;
    int r0 = w * 16;
    short8 aq = *(const short8*)&qkvb[(size_t)(i0 + r0 + m) * 768 + hh * DH + quad * 8];
    float m_st[4], l_st[4];
    #pragma unroll
    for (int r = 0; r < 4; r++) { m_st[r] = -3.0e38f; l_st[r] = 0.f; }
    f32x4 oacc[2] = {{0.f, 0.f, 0.f, 0.f}, {0.f, 0.f, 0.f, 0.f}};
    const float scale = 0.17677669529663687f;

    // wave-private bucket/bias addressing: 16 rows x 64 cols per wave
    int browq = r0 + (lane >> 2);        // own quadrant row
    int bcolq = (lane & 3) * 16;

    for (int jt = 0; jt < N_NODES / JSPLIT / 64; jt++) {
        int j0 = js * (N_NODES / JSPLIT) + jt * 64;
        // K fragments direct from global (coalesced 16x64B, L2-hit)
        short8 bk8[4];
        #pragma unroll
        for (int t = 0; t < 4; t++)
            bk8[t] = *(const short8*)&qkvb[(size_t)(j0 + t * 16 + m) * 768 + 256 + hh * DH + quad * 8];
        {   // own-quadrant bias rows: bucket gather + spd bpermute, vectorized store
            uint4 b16 = *(const uint4*)&bucket[(size_t)(i0 + browq) * N_NODES + j0 + bcolq];
            const unsigned char* bb = (const unsigned char*)&b16;
            float fb[16];
            #pragma unroll
            for (int i = 0; i < 16; i++)
                fb[i] = __int_as_float(
                    __builtin_amdgcn_ds_bpermute(((int)bb[i]) << 2, __float_as_int(spd_reg)));
            #pragma unroll
            for (int g = 0; g < 4; g++) {
                f32x4 st = {fb[g * 4], fb[g * 4 + 1], fb[g * 4 + 2], fb[g * 4 + 3]};
                *(f32x4*)&ov[browq][bcolq + g * 4] = st;
            }
        }
        __builtin_amdgcn_s_waitcnt(0xC07F);   // lgkmcnt(0): own-wave bias stores visible
        {   // sparse edge bias, filtered to own rows (each wave scans segment at lane stride)
            unsigned key0 = (unsigned)rb * 2048 + j0;
            unsigned start = offsets[key0], end = offsets[key0 + 64];
            for (unsigned i = start + lane; i < end; i += 64) {
                unsigned p = packed[i];
                int sl = (p >> 11) & 63;
                if (sl >= r0 && sl < r0 + 16) {
                    float ev = __int_as_float(
                        __builtin_amdgcn_ds_bpermute((int)((p >> 17) & 7) << 2,
                                                     __float_as_int(et_reg)));
                    atomicAdd(&ov[sl][(p & 2047) - j0], ev);
                }
            }
        }
        __builtin_amdgcn_s_waitcnt(0xC07F);   // lgkmcnt(0): own-wave edge atomics done
        // S = QK^T*scale + bias (C-layout registers; reads own quadrant only)
        float sv[4][4];
        #pragma unroll
        for (int t = 0; t < 4; t++) {
            f32x4 z = {0.f, 0.f, 0.f, 0.f};
            f32x4 sacc = __builtin_amdgcn_mfma_f32_16x16x32_bf16(aq, bk8[t], z, 0, 0, 0);
            #pragma unroll
            for (int r = 0; r < 4; r++)
                sv[t][r] = sacc[r] * scale + ov[r0 + quad * 4 + r][t * 16 + m];
        }
        // V fragments direct from global; softmax below hides the latency
        short8 vb[2][2];
        #pragma unroll
        for (int t = 0; t < 2; t++)
            #pragma unroll
            for (int kh = 0; kh < 2; kh++)
                vb[t][kh] = *(const short8*)&vbt[(size_t)(hh * DH + t * 16 + m) * N_NODES +
                                                 j0 + kh * 32 + quad * 8];
        // online softmax: 16-lane row reductions via DPP rotates (VALU pipe)
        float alpha[4];
        #pragma unroll
        for (int r = 0; r < 4; r++) {
            float mx = fmaxf(fmaxf(sv[0][r], sv[1][r]), fmaxf(sv[2][r], sv[3][r]));
            mx = fmaxf(mx, dpp_ror<0x121>(mx));
            mx = fmaxf(mx, dpp_ror<0x122>(mx));
            mx = fmaxf(mx, dpp_ror<0x124>(mx));
            mx = fmaxf(mx, dpp_ror<0x128>(mx));
            float mn = fmaxf(m_st[r], mx);
            alpha[r] = __expf(m_st[r] - mn);
            m_st[r] = mn;
            float ps = 0.f;
            #pragma unroll
            for (int t = 0; t < 4; t++) { float pv = __expf(sv[t][r] - mn); sv[t][r] = pv; ps += pv; }
            ps += dpp_ror<0x121>(ps);
            ps += dpp_ror<0x122>(ps);
            ps += dpp_ror<0x124>(ps);
            ps += dpp_ror<0x128>(ps);
            l_st[r] = l_st[r] * alpha[r] + ps;
        }
        // float P into own quadrant (C-layout write, 2-way banks)
        #pragma unroll
        for (int t = 0; t < 4; t++)
            #pragma unroll
            for (int r = 0; r < 4; r++)
                ov[r0 + quad * 4 + r][t * 16 + m] = sv[t][r];
        #pragma unroll
        for (int r = 0; r < 4; r++) { oacc[0][r] *= alpha[r]; oacc[1][r] *= alpha[r]; }
        __builtin_amdgcn_s_waitcnt(0xC07F);   // lgkmcnt(0): own-wave P writes visible
        #pragma unroll
        for (int kh = 0; kh < 2; kh++) {
            f32x4 p0 = *(const f32x4*)&ov[r0 + m][kh * 32 + quad * 8];
            f32x4 p1 = *(const f32x4*)&ov[r0 + m][kh * 32 + quad * 8 + 4];
            short8 pa;
            pa[0] = (short)f2bf(p0[0]); pa[1] = (short)f2bf(p0[1]);
            pa[2] = (short)f2bf(p0[2]); pa[3] = (short)f2bf(p0[3]);
            pa[4] = (short)f2bf(p1[0]); pa[5] = (short)f2bf(p1[1]);
            pa[6] = (short)f2bf(p1[2]); pa[7] = (short)f2bf(p1[3]);
            #pragma unroll
            for (int t = 0; t < 2; t++)
                oacc[t] = __builtin_amdgcn_mfma_f32_16x16x32_bf16(pa, vb[t][kh], oacc[t], 0, 0, 0);
        }
        __builtin_amdgcn_s_waitcnt(0xC07F);   // P reads done before next tile overwrites ov
    }
    #pragma unroll
    for (int t = 0; t < 2; t++)
        #pragma unroll
        for (int r = 0; r < 4; r++)
            part_O[((size_t)js * N_NODES + i0 + r0 + quad * 4 + r) * D_MODEL + hh * DH + t * 16 + m] =
                oacc[t][r];
    if (m == 0) {
        #pragma unroll
        for (int r = 0; r < 4; r++) {
            int row = i0 + r0 + quad * 4 + r;
            m_part[((size_t)js * NHEAD + hh) * N_NODES + row] = m_st[r];
            l_part[((size_t)js * NHEAD + hh) * N_NODES + row] = l_st[r];
        }
    }
}

// ---------------- merge j-split partials -> bf16 attn out ----------------
__global__ void flash_merge_kernel(const float* __restrict__ part_O,
                                   const float* __restrict__ m_part,
                                   const float* __restrict__ l_part,
                                   unsigned short* __restrict__ aoutb) {
    int e = blockIdx.x * 256 + threadIdx.x;
    int row = e >> 8, col = e & 255, h = col >> 5;
    float mv[JSPLIT];
    float mg = -3.0e38f;
    #pragma unroll
    for (int js = 0; js < JSPLIT; js++) {
        mv[js] = m_part[((size_t)js * NHEAD + h) * N_NODES + row];
        mg = fmaxf(mg, mv[js]);
    }
    float o = 0.f, l = 0.f;
    #pragma unroll
    for (int js = 0; js < JSPLIT; js++) {
        float sc = __expf(mv[js] - mg);
        o += sc * part_O[(size_t)js * N_NODES * D_MODEL + e];
        l += sc * l_part[((size_t)js * NHEAD + h) * N_NODES + row];
    }
    aoutb[e] = f2bf(o / l);
}

// 256-byte-aligned workspace allocation
#define WS_ALLOC(type, name, count) \
    type* name = (type*)base; base += (((size_t)(count) * sizeof(type)) + 255) & ~(size_t)255;

extern "C" void kernel_launch(void* const* d_in, const int* in_sizes, int n_in,
                              void* d_out, int out_size, void* d_ws, size_t ws_size,
                              hipStream_t stream) {
    const float* x          = (const float*)d_in[0];
    const int*   edge_index = (const int*)d_in[1];
    const int*   edge_types = (const int*)d_in[2];
    const float* pos        = (const float*)d_in[3];
    const float* W_emb      = (const float*)d_in[4];
    const float* b_emb      = (const float*)d_in[5];
    const float* Wq         = (const float*)d_in[6];
    const float* Wk         = (const float*)d_in[7];
    const float* Wv         = (const float*)d_in[8];
    const float* Wo         = (const float*)d_in[9];
    const float* bq         = (const float*)d_in[10];
    const float* bk         = (const float*)d_in[11];
    const float* bv         = (const float*)d_in[12];
    const float* bo         = (const float*)d_in[13];
    const float* spd_table  = (const float*)d_in[14];
    const float* edge_table = (const float*)d_in[15];
    const float* din_emb    = (const float*)d_in[16];
    const float* dout_emb   = (const float*)d_in[17];
    const float* ln1_g      = (const float*)d_in[18];
    const float* ln1_b      = (const float*)d_in[19];
    const float* ln2_g      = (const float*)d_in[20];
    const float* ln2_b      = (const float*)d_in[21];
    const float* W1         = (const float*)d_in[22];
    const float* b1         = (const float*)d_in[23];
    const float* W2         = (const float*)d_in[24];
    const float* b2         = (const float*)d_in[25];
    const float* W_out      = (const float*)d_in[26];
    const float* b_out      = (const float*)d_in[27];
    float* out = (float*)d_out;

    char* base = (char*)d_ws;
    WS_ALLOC(int, deg_out, N_NODES)
    WS_ALLOC(int, deg_in, N_NODES)
    WS_ALLOC(float, h, N_NODES * D_MODEL)
    WS_ALLOC(unsigned short, xb, N_NODES * D_MODEL)
    WS_ALLOC(unsigned short, qkvb, N_NODES * 768)
    WS_ALLOC(unsigned short, vbt, D_MODEL * N_NODES)
    WS_ALLOC(unsigned short, aoutb, N_NODES * D_MODEL)
    WS_ALLOC(unsigned short, ffnb, N_NODES * D_FF)
    WS_ALLOC(unsigned char, bucket, (size_t)N_NODES * N_NODES)
    WS_ALLOC(unsigned short, qkvt, NLAYER * 768 * D_MODEL)
    WS_ALLOC(unsigned short, wot, NLAYER * D_MODEL * D_MODEL)
    WS_ALLOC(unsigned short, w1t, NLAYER * D_MODEL * D_FF)
    WS_ALLOC(unsigned short, w2t, NLAYER * D_FF * D_MODEL)
    WS_ALLOC(unsigned short, wembt, D_FEAT * D_MODEL)
    WS_ALLOC(unsigned short, woutt, D_MODEL * D_OUT)
    WS_ALLOC(float, bqkv, NLAYER * 768)
    WS_ALLOC(unsigned, hist, 65536)
    WS_ALLOC(unsigned, offsets, 65537)
    WS_ALLOC(unsigned, cursor, 65536)
    WS_ALLOC(unsigned, blocksum, 256)
    WS_ALLOC(unsigned, packed, NEDGE)
    WS_ALLOC(float, part_O, (size_t)JSPLIT * N_NODES * D_MODEL)
    WS_ALLOC(float, m_part, (size_t)JSPLIT * NHEAD * N_NODES)
    WS_ALLOC(float, l_part, (size_t)JSPLIT * NHEAD * N_NODES)

    // ---- prep ----
    mega_prep_kernel<<<5702, 256, 0, stream>>>(pos, bucket, hist, deg_out, deg_in,
                                               Wq, Wk, Wv, Wo, W1, W2, W_emb, W_out,
                                               bq, bk, bv, qkvt, wot, w1t, w2t, wembt, woutt, bqkv);
    degree_hist_kernel<<<NEDGE / 256, 256, 0, stream>>>(edge_index, deg_out, deg_in, hist);
    edge_scan1_kernel<<<256, 256, 0, stream>>>(hist, offsets, blocksum);
    edge_scan2_kernel<<<1, 256, 0, stream>>>(blocksum);
    edge_scan3_kernel<<<256, 256, 0, stream>>>(blocksum, offsets, cursor);
    edge_scatter_kernel<<<NEDGE / 256, 256, 0, stream>>>(edge_index, edge_types, cursor, packed);

    // embed: h = x @ W_emb + b_emb (fp32 A, cast in staging)
    gemm_mfma_kernel<0, false, false, true><<<dim3(D_MODEL / 64, N_NODES / 32), 256, 0, stream>>>(
        x, wembt, b_emb, h, nullptr, D_MODEL, D_FEAT);

    for (int l = 0; l < NLAYER; l++) {
        centrality_ln_kernel<<<N_NODES, 256, 0, stream>>>(
            h, din_emb + (size_t)l * (MAXDEG + 1) * D_MODEL,
            dout_emb + (size_t)l * (MAXDEG + 1) * D_MODEL, deg_in, deg_out,
            ln1_g + l * D_MODEL, ln1_b + l * D_MODEL, xb);

        gemm64_kernel<0, true><<<dim3(768 / 64, N_NODES / 64), 256, 0, stream>>>(
            xb, qkvt + (size_t)l * 768 * D_MODEL, bqkv + l * 768, qkvb, vbt, 768, D_MODEL);

        flash_attn_kernel<<<dim3(N_NODES / 64, NHEAD, JSPLIT), 256, 0, stream>>>(
            qkvb, vbt, bucket, spd_table + (size_t)l * 11 * NHEAD,
            edge_table + (size_t)l * 8 * NHEAD, offsets, packed, part_O, m_part, l_part);

        flash_merge_kernel<<<N_NODES * D_MODEL / 256, 256, 0, stream>>>(part_O, m_part, l_part, aoutb);

        // O-proj: h += aout @ Wo + bo
        gemm_mfma_kernel<0, true, false, false><<<dim3(D_MODEL / 64, N_NODES / 32), 256, 0, stream>>>(
            aoutb, wot + (size_t)l * D_MODEL * D_MODEL, bo + l * D_MODEL, h, nullptr, D_MODEL, D_MODEL);

        layernorm_kernel<<<N_NODES, 256, 0, stream>>>(h, ln2_g + l * D_MODEL, ln2_b + l * D_MODEL, xb);

        gemm64_kernel<1, false><<<dim3(D_FF / 64, N_NODES / 64), 256, 0, stream>>>(
            xb, w1t + (size_t)l * D_MODEL * D_FF, b1 + l * D_FF, ffnb, nullptr, D_FF, D_MODEL);

        gemm_mfma_kernel<0, true, false, false><<<dim3(D_MODEL / 64, N_NODES / 32), 256, 0, stream>>>(
            ffnb, w2t + (size_t)l * D_FF * D_MODEL, b2 + l * D_MODEL, h, nullptr, D_MODEL, D_FF);
    }

    // final: out = h @ W_out + b_out (fp32 A, cast in staging)
    gemm_mfma_kernel<0, false, false, true><<<dim3(D_OUT / 64, N_NODES / 32), 256, 0, stream>>>(
        h, woutt, b_out, out, nullptr, D_OUT, D_MODEL);
}

// Round 14
// 307.355 us; speedup vs baseline: 1.0521x; 1.0300x over previous
//
#include <hip/hip_runtime.h>
#include <math.h>

#define N_NODES 2048
#define D_MODEL 256
#define D_FEAT 128
#define NHEAD 8
#define DH 32
#define NLAYER 2
#define NEDGE 65536
#define D_FF 1024
#define D_OUT 128
#define MAXDEG 512
#define JSPLIT 4

typedef __attribute__((ext_vector_type(8))) short short8;
typedef __attribute__((ext_vector_type(4))) float f32x4;
typedef __attribute__((ext_vector_type(4))) unsigned short u16x4;

__device__ __forceinline__ unsigned short f2bf(float f) {
    unsigned u = __float_as_uint(f);
    unsigned r = (u + 0x7FFFu + ((u >> 16) & 1u)) >> 16;
    return (unsigned short)r;
}

template <int CTRL>
__device__ __forceinline__ float dpp_ror(float x) {
    return __int_as_float(__builtin_amdgcn_update_dpp(0, __float_as_int(x), CTRL, 0xf, 0xf, false));
}

// ---------------- mega prep: bucket table + zeroing + all weight transposes ----------------
__device__ __forceinline__ void wt_tile(const float* __restrict__ W, unsigned short* __restrict__ Wt,
                                        int K, int Nc, int n0, int k0, int tid,
                                        unsigned short (*tile)[33]) {
    int r = tid >> 3, cg = (tid & 7) * 4;
    float4 w4 = *(const float4*)&W[(size_t)(k0 + r) * Nc + n0 + cg];
    tile[r][cg + 0] = f2bf(w4.x); tile[r][cg + 1] = f2bf(w4.y);
    tile[r][cg + 2] = f2bf(w4.z); tile[r][cg + 3] = f2bf(w4.w);
    __syncthreads();
    int c = tid >> 3, rg = (tid & 7) * 4;
    u16x4 o;
    #pragma unroll
    for (int j = 0; j < 4; j++) o[j] = tile[rg + j][c];
    *(u16x4*)&Wt[(size_t)(n0 + c) * K + k0 + rg] = o;
}

__global__ void mega_prep_kernel(const float* __restrict__ pos, unsigned char* __restrict__ bucket,
                                 unsigned* __restrict__ hist, int* __restrict__ deg_out,
                                 int* __restrict__ deg_in,
                                 const float* __restrict__ Wq, const float* __restrict__ Wk,
                                 const float* __restrict__ Wv, const float* __restrict__ Wo,
                                 const float* __restrict__ W1, const float* __restrict__ W2,
                                 const float* __restrict__ W_emb, const float* __restrict__ W_out,
                                 const float* __restrict__ bq, const float* __restrict__ bk,
                                 const float* __restrict__ bv,
                                 unsigned short* __restrict__ qkvt, unsigned short* __restrict__ wot,
                                 unsigned short* __restrict__ w1t, unsigned short* __restrict__ w2t,
                                 unsigned short* __restrict__ wembt, unsigned short* __restrict__ woutt,
                                 float* __restrict__ bqkv) {
    __shared__ unsigned short tile[32][33];
    int b = blockIdx.x, tid = threadIdx.x;
    if (b < 4096) {
        int i = b * 256 + tid;
        float4 p = *(const float4*)&pos[(size_t)i * 4];
        unsigned b0 = (unsigned)fminf(fmaxf(p.x * 10.f + 0.5f, 0.f), 10.f);
        unsigned b1 = (unsigned)fminf(fmaxf(p.y * 10.f + 0.5f, 0.f), 10.f);
        unsigned b2 = (unsigned)fminf(fmaxf(p.z * 10.f + 0.5f, 0.f), 10.f);
        unsigned b3 = (unsigned)fminf(fmaxf(p.w * 10.f + 0.5f, 0.f), 10.f);
        ((unsigned*)bucket)[i] = b0 | (b1 << 8) | (b2 << 16) | (b3 << 24);
        if (b < 64) {
            #pragma unroll
            for (int k = 0; k < 4; k++) hist[b * 1024 + k * 256 + tid] = 0;
        } else if (b == 64) {
            #pragma unroll
            for (int k = 0; k < 8; k++) deg_out[k * 256 + tid] = 0;
            #pragma unroll
            for (int k = 0; k < 8; k++) deg_in[k * 256 + tid] = 0;
        }
        return;
    }
    int bb = b - 4096;
    if (bb < 512) {
        int z = bb >> 6, t = bb & 63;
        int l = z >> 2, which = z & 3;
        const float* W = (which == 0 ? Wq : which == 1 ? Wk : which == 2 ? Wv : Wo) + (size_t)l * 65536;
        unsigned short* dst = (which < 3) ? qkvt + (size_t)l * 196608 + which * 65536
                                          : wot + (size_t)l * 65536;
        wt_tile(W, dst, 256, 256, (t & 7) * 32, (t >> 3) * 32, tid, tile);
    } else if (bb < 1024) {
        int b2 = bb - 512, l = b2 >> 8, t = b2 & 255;
        wt_tile(W1 + (size_t)l * D_MODEL * D_FF, w1t + (size_t)l * D_MODEL * D_FF,
                D_MODEL, D_FF, (t & 31) * 32, (t >> 5) * 32, tid, tile);
    } else if (bb < 1536) {
        int b3 = bb - 1024, l = b3 >> 8, t = b3 & 255;
        wt_tile(W2 + (size_t)l * D_FF * D_MODEL, w2t + (size_t)l * D_FF * D_MODEL,
                D_FF, D_MODEL, (t & 7) * 32, (t >> 3) * 32, tid, tile);
    } else if (bb < 1568) {
        int b4 = bb - 1536;
        wt_tile(W_emb, wembt, D_FEAT, D_MODEL, (b4 & 7) * 32, (b4 >> 3) * 32, tid, tile);
    } else if (bb < 1600) {
        int b5 = bb - 1568;
        wt_tile(W_out, woutt, D_MODEL, D_OUT, (b5 & 3) * 32, (b5 >> 2) * 32, tid, tile);
    } else {
        int i = (bb - 1600) * 256 + tid;
        if (i < NLAYER * 768) {
            int l = i / 768, j = i % 768;
            const float* src = j < 256 ? bq : j < 512 ? bk : bv;
            bqkv[i] = src[l * 256 + (j & 255)];
        }
    }
}

// ---------------- degree + edge histogram ----------------
__global__ void degree_hist_kernel(const int* __restrict__ ei,
                                   int* __restrict__ deg_out, int* __restrict__ deg_in,
                                   unsigned* __restrict__ hist) {
    int e = blockIdx.x * 256 + threadIdx.x;
    if (e < NEDGE) {
        int src = ei[e], dst = ei[NEDGE + e];
        atomicAdd(&deg_out[src], 1);
        atomicAdd(&deg_in[dst], 1);
        atomicAdd(&hist[(src >> 6) * 2048 + dst], 1);
    }
}

// ---------------- 3-kernel coalesced parallel scan ----------------
__global__ void edge_scan1_kernel(const unsigned* __restrict__ hist,
                                  unsigned* __restrict__ offsets, unsigned* __restrict__ blocksum) {
    __shared__ unsigned tmp[256];
    int t = threadIdx.x;
    int g = blockIdx.x * 256 + t;
    unsigned v = hist[g];
    tmp[t] = v; __syncthreads();
    for (int off = 1; off < 256; off <<= 1) {
        unsigned u = (t >= off) ? tmp[t - off] : 0;
        __syncthreads();
        tmp[t] += u;
        __syncthreads();
    }
    offsets[g] = tmp[t] - v;
    if (t == 255) blocksum[blockIdx.x] = tmp[255];
}

__global__ void edge_scan2_kernel(unsigned* __restrict__ blocksum) {
    __shared__ unsigned tmp[256];
    int t = threadIdx.x;
    unsigned v = blocksum[t];
    tmp[t] = v; __syncthreads();
    for (int off = 1; off < 256; off <<= 1) {
        unsigned u = (t >= off) ? tmp[t - off] : 0;
        __syncthreads();
        tmp[t] += u;
        __syncthreads();
    }
    blocksum[t] = tmp[t] - v;
}

__global__ void edge_scan3_kernel(const unsigned* __restrict__ blocksum,
                                  unsigned* __restrict__ offsets, unsigned* __restrict__ cursor) {
    int g = blockIdx.x * 256 + threadIdx.x;
    unsigned o = offsets[g] + blocksum[blockIdx.x];
    offsets[g] = o; cursor[g] = o;
    if (g == 0) offsets[65536] = NEDGE;
}

__global__ void edge_scatter_kernel(const int* __restrict__ ei, const int* __restrict__ etypes,
                                    unsigned* __restrict__ cursor, unsigned* __restrict__ packed) {
    int e = blockIdx.x * 256 + threadIdx.x;
    if (e < NEDGE) {
        int src = ei[e], dst = ei[NEDGE + e];
        int key = (src >> 6) * 2048 + dst;
        unsigned pos = atomicAdd(&cursor[key], 1);
        packed[pos] = (unsigned)dst | ((unsigned)(src & 63) << 11) | ((unsigned)etypes[e] << 17);
    }
}

// ---------------- fused centrality + layernorm1 ----------------
__global__ void centrality_ln_kernel(float* __restrict__ h,
                                     const float* __restrict__ din_l,
                                     const float* __restrict__ dout_l,
                                     const int* __restrict__ deg_in,
                                     const int* __restrict__ deg_out,
                                     const float* __restrict__ g,
                                     const float* __restrict__ b,
                                     unsigned short* __restrict__ y) {
    int row = blockIdx.x;
    int tid = threadIdx.x;
    int di = min(max(deg_in[row], 0), MAXDEG);
    int dn = min(max(deg_out[row], 0), MAXDEG);
    float v = h[row * D_MODEL + tid] + din_l[di * D_MODEL + tid] + dout_l[dn * D_MODEL + tid];
    h[row * D_MODEL + tid] = v;
    __shared__ float red[256];
    red[tid] = v; __syncthreads();
    for (int s = 128; s > 0; s >>= 1) { if (tid < s) red[tid] += red[tid + s]; __syncthreads(); }
    float mu = red[0] * (1.0f / D_MODEL);
    __syncthreads();
    float d = v - mu;
    red[tid] = d * d; __syncthreads();
    for (int s = 128; s > 0; s >>= 1) { if (tid < s) red[tid] += red[tid + s]; __syncthreads(); }
    float rstd = rsqrtf(red[0] * (1.0f / D_MODEL) + 1e-5f);
    y[row * D_MODEL + tid] = f2bf(d * rstd * g[tid] + b[tid]);
}

// ---------------- layernorm2 ----------------
__global__ void layernorm_kernel(const float* __restrict__ x,
                                 const float* __restrict__ g,
                                 const float* __restrict__ b,
                                 unsigned short* __restrict__ y) {
    int row = blockIdx.x;
    int tid = threadIdx.x;
    float v = x[row * D_MODEL + tid];
    __shared__ float red[256];
    red[tid] = v; __syncthreads();
    for (int s = 128; s > 0; s >>= 1) { if (tid < s) red[tid] += red[tid + s]; __syncthreads(); }
    float mu = red[0] * (1.0f / D_MODEL);
    __syncthreads();
    float d = v - mu;
    red[tid] = d * d; __syncthreads();
    for (int s = 128; s > 0; s >>= 1) { if (tid < s) red[tid] += red[tid + s]; __syncthreads(); }
    float rstd = rsqrtf(red[0] * (1.0f / D_MODEL) + 1e-5f);
    y[row * D_MODEL + tid] = f2bf(d * rstd * g[tid] + b[tid]);
}

// ---------------- vbt transpose: qkvb v-slice [N][256] -> vbt [256][N] (coalesced both sides) ----------------
__global__ void vbt_t_kernel(const unsigned short* __restrict__ qkvb,
                             unsigned short* __restrict__ vbt) {
    __shared__ unsigned short tile[32][33];
    int c0 = blockIdx.x * 32, r0 = blockIdx.y * 32;
    int tid = threadIdx.x;
    int r = tid >> 3, cg = (tid & 7) * 4;
    u16x4 v4 = *(const u16x4*)&qkvb[(size_t)(r0 + r) * 768 + 512 + c0 + cg];
    tile[r][cg + 0] = v4[0]; tile[r][cg + 1] = v4[1];
    tile[r][cg + 2] = v4[2]; tile[r][cg + 3] = v4[3];
    __syncthreads();
    int c = tid >> 3, rg = (tid & 7) * 4;
    u16x4 o;
    #pragma unroll
    for (int j = 0; j < 4; j++) o[j] = tile[rg + j][c];
    *(u16x4*)&vbt[(size_t)(c0 + c) * N_NODES + r0 + rg] = o;
}

// ---------------- bf16 MFMA GEMM, 32x64 tile, prefetched K-loop ----------------
template <int ACT, bool RESID, bool OUTBF16, bool AFP32>
__global__ void gemm_mfma_kernel(const void* __restrict__ Av,
                                 const unsigned short* __restrict__ Wt,
                                 const float* __restrict__ bias,
                                 float* __restrict__ C, unsigned short* __restrict__ Cb,
                                 int Nc, int K) {
    __shared__ __align__(16) unsigned short As[32][72];
    __shared__ __align__(16) unsigned short Bs[64][72];
    const unsigned short* A16 = (const unsigned short*)Av;
    const float* A32 = (const float*)Av;
    int tid = threadIdx.x;
    int m0 = blockIdx.y * 32, n0 = blockIdx.x * 64;
    int w = tid >> 6, lane = tid & 63;
    int rg = (w & 1) * 16, cg = (w >> 1) * 32;
    int m = lane & 15, quad = lane >> 4;
    f32x4 acc[2] = {{0.f, 0.f, 0.f, 0.f}, {0.f, 0.f, 0.f, 0.f}};
    int ar = tid >> 3, ac = (tid & 7) * 8;
    uint4 ra; float4 fa0, fa1; uint4 rb0, rb1;
    if (AFP32) {
        fa0 = *(const float4*)&A32[(size_t)(m0 + ar) * K + ac];
        fa1 = *(const float4*)&A32[(size_t)(m0 + ar) * K + ac + 4];
    } else {
        ra = *(const uint4*)&A16[(size_t)(m0 + ar) * K + ac];
    }
    rb0 = *(const uint4*)&Wt[(size_t)(n0 + ar) * K + ac];
    rb1 = *(const uint4*)&Wt[(size_t)(n0 + 32 + ar) * K + ac];
    for (int k0 = 0; k0 < K; k0 += 64) {
        if (AFP32) {
            u16x4 t0 = {f2bf(fa0.x), f2bf(fa0.y), f2bf(fa0.z), f2bf(fa0.w)};
            u16x4 t1 = {f2bf(fa1.x), f2bf(fa1.y), f2bf(fa1.z), f2bf(fa1.w)};
            *(u16x4*)&As[ar][ac] = t0;
            *(u16x4*)&As[ar][ac + 4] = t1;
        } else {
            *(uint4*)&As[ar][ac] = ra;
        }
        *(uint4*)&Bs[ar][ac] = rb0;
        *(uint4*)&Bs[ar + 32][ac] = rb1;
        __syncthreads();
        int kn = k0 + 64;
        if (kn < K) {
            if (AFP32) {
                fa0 = *(const float4*)&A32[(size_t)(m0 + ar) * K + kn + ac];
                fa1 = *(const float4*)&A32[(size_t)(m0 + ar) * K + kn + ac + 4];
            } else {
                ra = *(const uint4*)&A16[(size_t)(m0 + ar) * K + kn + ac];
            }
            rb0 = *(const uint4*)&Wt[(size_t)(n0 + ar) * K + kn + ac];
            rb1 = *(const uint4*)&Wt[(size_t)(n0 + 32 + ar) * K + kn + ac];
        }
        #pragma unroll
        for (int ks = 0; ks < 2; ks++) {
            short8 a = *(const short8*)&As[rg + m][ks * 32 + quad * 8];
            #pragma unroll
            for (int t = 0; t < 2; t++) {
                short8 b = *(const short8*)&Bs[cg + t * 16 + m][ks * 32 + quad * 8];
                acc[t] = __builtin_amdgcn_mfma_f32_16x16x32_bf16(a, b, acc[t], 0, 0, 0);
            }
        }
        __syncthreads();
    }
    #pragma unroll
    for (int t = 0; t < 2; t++) {
        #pragma unroll
        for (int reg = 0; reg < 4; reg++) {
            int row = m0 + rg + quad * 4 + reg;
            int col = n0 + cg + t * 16 + m;
            float val = acc[t][reg] + bias[col];
            if (ACT == 1) val = val * 0.5f * (1.0f + erff(val * 0.7071067811865476f));
            size_t idx = (size_t)row * Nc + col;
            if (RESID) val += C[idx];
            if (OUTBF16) Cb[idx] = f2bf(val);
            else C[idx] = val;
        }
    }
}

// ---------------- O-proj GEMM with in-staging flash merge: h += merge(part_O) @ Wo + bo ----------------
// A fragment = bf16(merge over JSPLIT of part_O with m/l rescale), computed during LDS staging.
__global__ void gemm_oproj_kernel(const float* __restrict__ part_O,
                                  const float* __restrict__ m_part,
                                  const float* __restrict__ l_part,
                                  const unsigned short* __restrict__ Wt,
                                  const float* __restrict__ bias,
                                  float* __restrict__ C) {
    __shared__ __align__(16) unsigned short As[32][72];
    __shared__ __align__(16) unsigned short Bs[64][72];
    int tid = threadIdx.x;
    int m0 = blockIdx.y * 32, n0 = blockIdx.x * 64;
    int w = tid >> 6, lane = tid & 63;
    int rg = (w & 1) * 16, cg = (w >> 1) * 32;
    int m = lane & 15, quad = lane >> 4;
    f32x4 acc[2] = {{0.f, 0.f, 0.f, 0.f}, {0.f, 0.f, 0.f, 0.f}};
    int ar = tid >> 3, ac = (tid & 7) * 8;
    int row = m0 + ar;
    for (int k0 = 0; k0 < D_MODEL; k0 += 64) {
        int col = k0 + ac;
        int hh = col >> 5;                      // 8 cols lie within one head
        float mv[JSPLIT], lv[JSPLIT];
        float mg = -3.0e38f;
        #pragma unroll
        for (int js = 0; js < JSPLIT; js++) {
            mv[js] = m_part[((size_t)js * NHEAD + hh) * N_NODES + row];
            lv[js] = l_part[((size_t)js * NHEAD + hh) * N_NODES + row];
            mg = fmaxf(mg, mv[js]);
        }
        float o[8] = {0.f, 0.f, 0.f, 0.f, 0.f, 0.f, 0.f, 0.f};
        float L = 0.f;
        #pragma unroll
        for (int js = 0; js < JSPLIT; js++) {
            float sc = __expf(mv[js] - mg);
            L += sc * lv[js];
            const float* pp = &part_O[((size_t)js * N_NODES + row) * D_MODEL + col];
            float4 p0 = *(const float4*)pp;
            float4 p1 = *(const float4*)(pp + 4);
            o[0] += sc * p0.x; o[1] += sc * p0.y; o[2] += sc * p0.z; o[3] += sc * p0.w;
            o[4] += sc * p1.x; o[5] += sc * p1.y; o[6] += sc * p1.z; o[7] += sc * p1.w;
        }
        float inv = 1.0f / L;
        u16x4 t0, t1;
        #pragma unroll
        for (int j = 0; j < 4; j++) { t0[j] = f2bf(o[j] * inv); t1[j] = f2bf(o[j + 4] * inv); }
        *(u16x4*)&As[ar][ac] = t0;
        *(u16x4*)&As[ar][ac + 4] = t1;
        *(uint4*)&Bs[ar][ac] = *(const uint4*)&Wt[(size_t)(n0 + ar) * D_MODEL + k0 + ac];
        *(uint4*)&Bs[ar + 32][ac] = *(const uint4*)&Wt[(size_t)(n0 + 32 + ar) * D_MODEL + k0 + ac];
        __syncthreads();
        #pragma unroll
        for (int ks = 0; ks < 2; ks++) {
            short8 a = *(const short8*)&As[rg + m][ks * 32 + quad * 8];
            #pragma unroll
            for (int t = 0; t < 2; t++) {
                short8 b = *(const short8*)&Bs[cg + t * 16 + m][ks * 32 + quad * 8];
                acc[t] = __builtin_amdgcn_mfma_f32_16x16x32_bf16(a, b, acc[t], 0, 0, 0);
            }
        }
        __syncthreads();
    }
    #pragma unroll
    for (int t = 0; t < 2; t++) {
        #pragma unroll
        for (int reg = 0; reg < 4; reg++) {
            int orow = m0 + rg + quad * 4 + reg;
            int ocol = n0 + cg + t * 16 + m;
            size_t idx = (size_t)orow * D_MODEL + ocol;
            C[idx] += acc[t][reg] + bias[ocol];
        }
    }
}

// ---------------- bf16 MFMA GEMM, 64x64 tile, prefetched ----------------
template <int ACT>
__global__ void gemm64_kernel(const unsigned short* __restrict__ A,
                              const unsigned short* __restrict__ Wt,
                              const float* __restrict__ bias,
                              unsigned short* __restrict__ Cb,
                              int Nc, int K) {
    __shared__ __align__(16) unsigned short As[64][72];
    __shared__ __align__(16) unsigned short Bs[64][72];
    int tid = threadIdx.x;
    int m0 = blockIdx.y * 64, n0 = blockIdx.x * 64;
    int w = tid >> 6, lane = tid & 63;
    int wr = (w & 1) * 32, wc = (w >> 1) * 32;
    int m = lane & 15, quad = lane >> 4;
    f32x4 acc[2][2] = {{{0.f,0.f,0.f,0.f},{0.f,0.f,0.f,0.f}},{{0.f,0.f,0.f,0.f},{0.f,0.f,0.f,0.f}}};
    int sr = tid >> 2, sg = (tid & 3) * 16;
    uint4 a0 = *(const uint4*)&A[(size_t)(m0 + sr) * K + sg];
    uint4 a1 = *(const uint4*)&A[(size_t)(m0 + sr) * K + sg + 8];
    uint4 b0 = *(const uint4*)&Wt[(size_t)(n0 + sr) * K + sg];
    uint4 b1 = *(const uint4*)&Wt[(size_t)(n0 + sr) * K + sg + 8];
    for (int k0 = 0; k0 < K; k0 += 64) {
        *(uint4*)&As[sr][sg] = a0;
        *(uint4*)&As[sr][sg + 8] = a1;
        *(uint4*)&Bs[sr][sg] = b0;
        *(uint4*)&Bs[sr][sg + 8] = b1;
        __syncthreads();
        int kn = k0 + 64;
        if (kn < K) {
            a0 = *(const uint4*)&A[(size_t)(m0 + sr) * K + kn + sg];
            a1 = *(const uint4*)&A[(size_t)(m0 + sr) * K + kn + sg + 8];
            b0 = *(const uint4*)&Wt[(size_t)(n0 + sr) * K + kn + sg];
            b1 = *(const uint4*)&Wt[(size_t)(n0 + sr) * K + kn + sg + 8];
        }
        #pragma unroll
        for (int kh = 0; kh < 2; kh++) {
            short8 x0 = *(const short8*)&As[wr + m][kh * 32 + quad * 8];
            short8 x1 = *(const short8*)&As[wr + 16 + m][kh * 32 + quad * 8];
            short8 y0 = *(const short8*)&Bs[wc + m][kh * 32 + quad * 8];
            short8 y1 = *(const short8*)&Bs[wc + 16 + m][kh * 32 + quad * 8];
            acc[0][0] = __builtin_amdgcn_mfma_f32_16x16x32_bf16(x0, y0, acc[0][0], 0, 0, 0);
            acc[0][1] = __builtin_amdgcn_mfma_f32_16x16x32_bf16(x0, y1, acc[0][1], 0, 0, 0);
            acc[1][0] = __builtin_amdgcn_mfma_f32_16x16x32_bf16(x1, y0, acc[1][0], 0, 0, 0);
            acc[1][1] = __builtin_amdgcn_mfma_f32_16x16x32_bf16(x1, y1, acc[1][1], 0, 0, 0);
        }
        __syncthreads();
    }
    #pragma unroll
    for (int mt = 0; mt < 2; mt++) {
        #pragma unroll
        for (int nt = 0; nt < 2; nt++) {
            #pragma unroll
            for (int reg = 0; reg < 4; reg++) {
                int row = m0 + wr + mt * 16 + quad * 4 + reg;
                int col = n0 + wc + nt * 16 + m;
                float val = acc[mt][nt][reg] + bias[col];
                if (ACT == 1) val = val * 0.5f * (1.0f + erff(val * 0.7071067811865476f));
                Cb[(size_t)row * Nc + col] = f2bf(val);
            }
        }
    }
}

// ---------------- flash attention (round-11 v4: LDS-staged K/V, block bias, JSPLIT=4) ----------------
__global__ __launch_bounds__(256)
void flash_attn_kernel(const unsigned short* __restrict__ qkvb,
                       const unsigned short* __restrict__ vbt,
                       const unsigned char* __restrict__ bucket,
                       const float* __restrict__ spd_l,
                       const float* __restrict__ et_l,
                       const unsigned* __restrict__ offsets,
                       const unsigned* __restrict__ packed,
                       float* __restrict__ part_O,
                       float* __restrict__ m_part, float* __restrict__ l_part) {
    __shared__ __align__(16) unsigned short ks[64][40];
    __shared__ __align__(16) unsigned short vs[32][72];
    __shared__ __align__(16) float ov[64][68];
    __shared__ float et[8];

    int tid = threadIdx.x;
    int rb = blockIdx.x;
    int i0 = rb * 64;
    int hh = blockIdx.y;
    int js = blockIdx.z;
    int lane = tid & 63;
    if (tid < 8) et[tid] = et_l[tid * NHEAD + hh];
    float spd_reg = spd_l[(lane < 11 ? lane : 10) * NHEAD + hh];

    int w = tid >> 6;
    int m = lane & 15, quad = lane >> 4;
    int r0 = w * 16;
    short8 aq = *(const short8*)&qkvb[(size_t)(i0 + r0 + m) * 768 + hh * DH + quad * 8];
    float m_st[4], l_st[4];
    #pragma unroll
    for (int r = 0; r < 4; r++) { m_st[r] = -3.0e38f; l_st[r] = 0.f; }
    f32x4 oacc[2] = {{0.f, 0.f, 0.f, 0.f}, {0.f, 0.f, 0.f, 0.f}};
    const float scale = 0.17677669529663687f;

    int krow = tid >> 2, kcol = (tid & 3) * 8;
    int vrow = tid >> 3, vcol = (tid & 7) * 8;
    int brow = tid >> 2, bcol = (tid & 3) * 16;

    for (int jt = 0; jt < N_NODES / JSPLIT / 64; jt++) {
        int j0 = js * (N_NODES / JSPLIT) + jt * 64;
        __syncthreads();
        *(uint4*)&ks[krow][kcol] =
            *(const uint4*)&qkvb[(size_t)(j0 + krow) * 768 + 256 + hh * DH + kcol];
        *(uint4*)&vs[vrow][vcol] =
            *(const uint4*)&vbt[(size_t)(hh * DH + vrow) * N_NODES + j0 + vcol];
        {
            uint4 b16 = *(const uint4*)&bucket[(size_t)(i0 + brow) * N_NODES + j0 + bcol];
            const unsigned char* bb = (const unsigned char*)&b16;
            float fb[16];
            #pragma unroll
            for (int i = 0; i < 16; i++)
                fb[i] = __int_as_float(
                    __builtin_amdgcn_ds_bpermute(((int)bb[i]) << 2, __float_as_int(spd_reg)));
            #pragma unroll
            for (int g = 0; g < 4; g++) {
                f32x4 st = {fb[g * 4], fb[g * 4 + 1], fb[g * 4 + 2], fb[g * 4 + 3]};
                *(f32x4*)&ov[brow][bcol + g * 4] = st;
            }
        }
        __syncthreads();
        {
            unsigned key0 = (unsigned)rb * 2048 + j0;
            unsigned start = offsets[key0], end = offsets[key0 + 64];
            for (unsigned i = start + tid; i < end; i += 256) {
                unsigned p = packed[i];
                atomicAdd(&ov[(p >> 11) & 63][(p & 2047) - j0], et[(p >> 17) & 7]);
            }
        }
        __syncthreads();
        float sv[4][4];
        #pragma unroll
        for (int t = 0; t < 4; t++) {
            short8 bk8 = *(const short8*)&ks[t * 16 + m][quad * 8];
            f32x4 z = {0.f, 0.f, 0.f, 0.f};
            f32x4 sacc = __builtin_amdgcn_mfma_f32_16x16x32_bf16(aq, bk8, z, 0, 0, 0);
            #pragma unroll
            for (int r = 0; r < 4; r++)
                sv[t][r] = sacc[r] * scale + ov[r0 + quad * 4 + r][t * 16 + m];
        }
        float alpha[4];
        #pragma unroll
        for (int r = 0; r < 4; r++) {
            float mx = fmaxf(fmaxf(sv[0][r], sv[1][r]), fmaxf(sv[2][r], sv[3][r]));
            mx = fmaxf(mx, dpp_ror<0x121>(mx));
            mx = fmaxf(mx, dpp_ror<0x122>(mx));
            mx = fmaxf(mx, dpp_ror<0x124>(mx));
            mx = fmaxf(mx, dpp_ror<0x128>(mx));
            float mn = fmaxf(m_st[r], mx);
            alpha[r] = __expf(m_st[r] - mn);
            m_st[r] = mn;
            float ps = 0.f;
            #pragma unroll
            for (int t = 0; t < 4; t++) { float pv = __expf(sv[t][r] - mn); sv[t][r] = pv; ps += pv; }
            ps += dpp_ror<0x121>(ps);
            ps += dpp_ror<0x122>(ps);
            ps += dpp_ror<0x124>(ps);
            ps += dpp_ror<0x128>(ps);
            l_st[r] = l_st[r] * alpha[r] + ps;
        }
        #pragma unroll
        for (int t = 0; t < 4; t++)
            #pragma unroll
            for (int r = 0; r < 4; r++)
                ov[r0 + quad * 4 + r][t * 16 + m] = sv[t][r];
        #pragma unroll
        for (int r = 0; r < 4; r++) { oacc[0][r] *= alpha[r]; oacc[1][r] *= alpha[r]; }
        __builtin_amdgcn_s_waitcnt(0xC07F);
        #pragma unroll
        for (int kh = 0; kh < 2; kh++) {
            f32x4 p0 = *(const f32x4*)&ov[r0 + m][kh * 32 + quad * 8];
            f32x4 p1 = *(const f32x4*)&ov[r0 + m][kh * 32 + quad * 8 + 4];
            short8 pa;
            pa[0] = (short)f2bf(p0[0]); pa[1] = (short)f2bf(p0[1]);
            pa[2] = (short)f2bf(p0[2]); pa[3] = (short)f2bf(p0[3]);
            pa[4] = (short)f2bf(p1[0]); pa[5] = (short)f2bf(p1[1]);
            pa[6] = (short)f2bf(p1[2]); pa[7] = (short)f2bf(p1[3]);
            #pragma unroll
            for (int t = 0; t < 2; t++) {
                short8 vb = *(const short8*)&vs[t * 16 + m][kh * 32 + quad * 8];
                oacc[t] = __builtin_amdgcn_mfma_f32_16x16x32_bf16(pa, vb, oacc[t], 0, 0, 0);
            }
        }
    }
    #pragma unroll
    for (int t = 0; t < 2; t++)
        #pragma unroll
        for (int r = 0; r < 4; r++)
            part_O[((size_t)js * N_NODES + i0 + r0 + quad * 4 + r) * D_MODEL + hh * DH + t * 16 + m] =
                oacc[t][r];
    if (m == 0) {
        #pragma unroll
        for (int r = 0; r < 4; r++) {
            int row = i0 + r0 + quad * 4 + r;
            m_part[((size_t)js * NHEAD + hh) * N_NODES + row] = m_st[r];
            l_part[((size_t)js * NHEAD + hh) * N_NODES + row] = l_st[r];
        }
    }
}

// 256-byte-aligned workspace allocation
#define WS_ALLOC(type, name, count) \
    type* name = (type*)base; base += (((size_t)(count) * sizeof(type)) + 255) & ~(size_t)255;

extern "C" void kernel_launch(void* const* d_in, const int* in_sizes, int n_in,
                              void* d_out, int out_size, void* d_ws, size_t ws_size,
                              hipStream_t stream) {
    const float* x          = (const float*)d_in[0];
    const int*   edge_index = (const int*)d_in[1];
    const int*   edge_types = (const int*)d_in[2];
    const float* pos        = (const float*)d_in[3];
    const float* W_emb      = (const float*)d_in[4];
    const float* b_emb      = (const float*)d_in[5];
    const float* Wq         = (const float*)d_in[6];
    const float* Wk         = (const float*)d_in[7];
    const float* Wv         = (const float*)d_in[8];
    const float* Wo         = (const float*)d_in[9];
    const float* bq         = (const float*)d_in[10];
    const float* bk         = (const float*)d_in[11];
    const float* bv         = (const float*)d_in[12];
    const float* bo         = (const float*)d_in[13];
    const float* spd_table  = (const float*)d_in[14];
    const float* edge_table = (const float*)d_in[15];
    const float* din_emb    = (const float*)d_in[16];
    const float* dout_emb   = (const float*)d_in[17];
    const float* ln1_g      = (const float*)d_in[18];
    const float* ln1_b      = (const float*)d_in[19];
    const float* ln2_g      = (const float*)d_in[20];
    const float* ln2_b      = (const float*)d_in[21];
    const float* W1         = (const float*)d_in[22];
    const float* b1         = (const float*)d_in[23];
    const float* W2         = (const float*)d_in[24];
    const float* b2         = (const float*)d_in[25];
    const float* W_out      = (const float*)d_in[26];
    const float* b_out      = (const float*)d_in[27];
    float* out = (float*)d_out;

    char* base = (char*)d_ws;
    WS_ALLOC(int, deg_out, N_NODES)
    WS_ALLOC(int, deg_in, N_NODES)
    WS_ALLOC(float, h, N_NODES * D_MODEL)
    WS_ALLOC(unsigned short, xb, N_NODES * D_MODEL)
    WS_ALLOC(unsigned short, qkvb, N_NODES * 768)
    WS_ALLOC(unsigned short, vbt, D_MODEL * N_NODES)
    WS_ALLOC(unsigned short, ffnb, N_NODES * D_FF)
    WS_ALLOC(unsigned char, bucket, (size_t)N_NODES * N_NODES)
    WS_ALLOC(unsigned short, qkvt, NLAYER * 768 * D_MODEL)
    WS_ALLOC(unsigned short, wot, NLAYER * D_MODEL * D_MODEL)
    WS_ALLOC(unsigned short, w1t, NLAYER * D_MODEL * D_FF)
    WS_ALLOC(unsigned short, w2t, NLAYER * D_FF * D_MODEL)
    WS_ALLOC(unsigned short, wembt, D_FEAT * D_MODEL)
    WS_ALLOC(unsigned short, woutt, D_MODEL * D_OUT)
    WS_ALLOC(float, bqkv, NLAYER * 768)
    WS_ALLOC(unsigned, hist, 65536)
    WS_ALLOC(unsigned, offsets, 65537)
    WS_ALLOC(unsigned, cursor, 65536)
    WS_ALLOC(unsigned, blocksum, 256)
    WS_ALLOC(unsigned, packed, NEDGE)
    WS_ALLOC(float, part_O, (size_t)JSPLIT * N_NODES * D_MODEL)
    WS_ALLOC(float, m_part, (size_t)JSPLIT * NHEAD * N_NODES)
    WS_ALLOC(float, l_part, (size_t)JSPLIT * NHEAD * N_NODES)

    // ---- prep ----
    mega_prep_kernel<<<5702, 256, 0, stream>>>(pos, bucket, hist, deg_out, deg_in,
                                               Wq, Wk, Wv, Wo, W1, W2, W_emb, W_out,
                                               bq, bk, bv, qkvt, wot, w1t, w2t, wembt, woutt, bqkv);
    degree_hist_kernel<<<NEDGE / 256, 256, 0, stream>>>(edge_index, deg_out, deg_in, hist);
    edge_scan1_kernel<<<256, 256, 0, stream>>>(hist, offsets, blocksum);
    edge_scan2_kernel<<<1, 256, 0, stream>>>(blocksum);
    edge_scan3_kernel<<<256, 256, 0, stream>>>(blocksum, offsets, cursor);
    edge_scatter_kernel<<<NEDGE / 256, 256, 0, stream>>>(edge_index, edge_types, cursor, packed);

    // embed: h = x @ W_emb + b_emb (fp32 A, cast in staging)
    gemm_mfma_kernel<0, false, false, true><<<dim3(D_MODEL / 64, N_NODES / 32), 256, 0, stream>>>(
        x, wembt, b_emb, h, nullptr, D_MODEL, D_FEAT);

    for (int l = 0; l < NLAYER; l++) {
        centrality_ln_kernel<<<N_NODES, 256, 0, stream>>>(
            h, din_emb + (size_t)l * (MAXDEG + 1) * D_MODEL,
            dout_emb + (size_t)l * (MAXDEG + 1) * D_MODEL, deg_in, deg_out,
            ln1_g + l * D_MODEL, ln1_b + l * D_MODEL, xb);

        gemm64_kernel<0><<<dim3(768 / 64, N_NODES / 64), 256, 0, stream>>>(
            xb, qkvt + (size_t)l * 768 * D_MODEL, bqkv + l * 768, qkvb, 768, D_MODEL);

        vbt_t_kernel<<<dim3(D_MODEL / 32, N_NODES / 32), 256, 0, stream>>>(qkvb, vbt);

        flash_attn_kernel<<<dim3(N_NODES / 64, NHEAD, JSPLIT), 256, 0, stream>>>(
            qkvb, vbt, bucket, spd_table + (size_t)l * 11 * NHEAD,
            edge_table + (size_t)l * 8 * NHEAD, offsets, packed, part_O, m_part, l_part);

        // O-proj with in-staging merge: h += merge(part_O) @ Wo + bo
        gemm_oproj_kernel<<<dim3(D_MODEL / 64, N_NODES / 32), 256, 0, stream>>>(
            part_O, m_part, l_part, wot + (size_t)l * D_MODEL * D_MODEL, bo + l * D_MODEL, h);

        layernorm_kernel<<<N_NODES, 256, 0, stream>>>(h, ln2_g + l * D_MODEL, ln2_b + l * D_MODEL, xb);

        gemm64_kernel<1><<<dim3(D_FF / 64, N_NODES / 64), 256, 0, stream>>>(
            xb, w1t + (size_t)l * D_MODEL * D_FF, b1 + l * D_FF, ffnb, D_FF, D_MODEL);

        gemm_mfma_kernel<0, true, false, false><<<dim3(D_MODEL / 64, N_NODES / 32), 256, 0, stream>>>(
            ffnb, w2t + (size_t)l * D_FF * D_MODEL, b2 + l * D_MODEL, h, nullptr, D_MODEL, D_FF);
    }

    // final: out = h @ W_out + b_out (fp32 A, cast in staging)
    gemm_mfma_kernel<0, false, false, true><<<dim3(D_OUT / 64, N_NODES / 32), 256, 0, stream>>>(
        h, woutt, b_out, out, nullptr, D_OUT, D_MODEL);
}

// Round 15
// 301.341 us; speedup vs baseline: 1.0731x; 1.0200x over previous
//
#include <hip/hip_runtime.h>
#include <math.h>

#define N_NODES 2048
#define D_MODEL 256
#define D_FEAT 128
#define NHEAD 8
#define DH 32
#define NLAYER 2
#define NEDGE 65536
#define D_FF 1024
#define D_OUT 128
#define MAXDEG 512
#define JSPLIT 4

typedef __attribute__((ext_vector_type(8))) short short8;
typedef __attribute__((ext_vector_type(4))) float f32x4;
typedef __attribute__((ext_vector_type(4))) unsigned short u16x4;

__device__ __forceinline__ unsigned short f2bf(float f) {
    unsigned u = __float_as_uint(f);
    unsigned r = (u + 0x7FFFu + ((u >> 16) & 1u)) >> 16;
    return (unsigned short)r;
}

template <int CTRL>
__device__ __forceinline__ float dpp_ror(float x) {
    return __int_as_float(__builtin_amdgcn_update_dpp(0, __float_as_int(x), CTRL, 0xf, 0xf, false));
}

// ---------------- mega prep: bucket table + zeroing + all weight transposes ----------------
__device__ __forceinline__ void wt_tile(const float* __restrict__ W, unsigned short* __restrict__ Wt,
                                        int K, int Nc, int n0, int k0, int tid,
                                        unsigned short (*tile)[33]) {
    int r = tid >> 3, cg = (tid & 7) * 4;
    float4 w4 = *(const float4*)&W[(size_t)(k0 + r) * Nc + n0 + cg];
    tile[r][cg + 0] = f2bf(w4.x); tile[r][cg + 1] = f2bf(w4.y);
    tile[r][cg + 2] = f2bf(w4.z); tile[r][cg + 3] = f2bf(w4.w);
    __syncthreads();
    int c = tid >> 3, rg = (tid & 7) * 4;
    u16x4 o;
    #pragma unroll
    for (int j = 0; j < 4; j++) o[j] = tile[rg + j][c];
    *(u16x4*)&Wt[(size_t)(n0 + c) * K + k0 + rg] = o;
}

__global__ void mega_prep_kernel(const float* __restrict__ pos, unsigned char* __restrict__ bucket,
                                 unsigned* __restrict__ hist, int* __restrict__ deg_out,
                                 int* __restrict__ deg_in,
                                 const float* __restrict__ Wq, const float* __restrict__ Wk,
                                 const float* __restrict__ Wv, const float* __restrict__ Wo,
                                 const float* __restrict__ W1, const float* __restrict__ W2,
                                 const float* __restrict__ W_emb, const float* __restrict__ W_out,
                                 const float* __restrict__ bq, const float* __restrict__ bk,
                                 const float* __restrict__ bv,
                                 unsigned short* __restrict__ qkvt, unsigned short* __restrict__ wot,
                                 unsigned short* __restrict__ w1t, unsigned short* __restrict__ w2t,
                                 unsigned short* __restrict__ wembt, unsigned short* __restrict__ woutt,
                                 float* __restrict__ bqkv) {
    __shared__ unsigned short tile[32][33];
    int b = blockIdx.x, tid = threadIdx.x;
    if (b < 4096) {
        int i = b * 256 + tid;
        float4 p = *(const float4*)&pos[(size_t)i * 4];
        unsigned b0 = (unsigned)fminf(fmaxf(p.x * 10.f + 0.5f, 0.f), 10.f);
        unsigned b1 = (unsigned)fminf(fmaxf(p.y * 10.f + 0.5f, 0.f), 10.f);
        unsigned b2 = (unsigned)fminf(fmaxf(p.z * 10.f + 0.5f, 0.f), 10.f);
        unsigned b3 = (unsigned)fminf(fmaxf(p.w * 10.f + 0.5f, 0.f), 10.f);
        ((unsigned*)bucket)[i] = b0 | (b1 << 8) | (b2 << 16) | (b3 << 24);
        if (b < 64) {
            #pragma unroll
            for (int k = 0; k < 4; k++) hist[b * 1024 + k * 256 + tid] = 0;
        } else if (b == 64) {
            #pragma unroll
            for (int k = 0; k < 8; k++) deg_out[k * 256 + tid] = 0;
            #pragma unroll
            for (int k = 0; k < 8; k++) deg_in[k * 256 + tid] = 0;
        }
        return;
    }
    int bb = b - 4096;
    if (bb < 512) {
        int z = bb >> 6, t = bb & 63;
        int l = z >> 2, which = z & 3;
        const float* W = (which == 0 ? Wq : which == 1 ? Wk : which == 2 ? Wv : Wo) + (size_t)l * 65536;
        unsigned short* dst = (which < 3) ? qkvt + (size_t)l * 196608 + which * 65536
                                          : wot + (size_t)l * 65536;
        wt_tile(W, dst, 256, 256, (t & 7) * 32, (t >> 3) * 32, tid, tile);
    } else if (bb < 1024) {
        int b2 = bb - 512, l = b2 >> 8, t = b2 & 255;
        wt_tile(W1 + (size_t)l * D_MODEL * D_FF, w1t + (size_t)l * D_MODEL * D_FF,
                D_MODEL, D_FF, (t & 31) * 32, (t >> 5) * 32, tid, tile);
    } else if (bb < 1536) {
        int b3 = bb - 1024, l = b3 >> 8, t = b3 & 255;
        wt_tile(W2 + (size_t)l * D_FF * D_MODEL, w2t + (size_t)l * D_FF * D_MODEL,
                D_FF, D_MODEL, (t & 7) * 32, (t >> 3) * 32, tid, tile);
    } else if (bb < 1568) {
        int b4 = bb - 1536;
        wt_tile(W_emb, wembt, D_FEAT, D_MODEL, (b4 & 7) * 32, (b4 >> 3) * 32, tid, tile);
    } else if (bb < 1600) {
        int b5 = bb - 1568;
        wt_tile(W_out, woutt, D_MODEL, D_OUT, (b5 & 3) * 32, (b5 >> 2) * 32, tid, tile);
    } else {
        int i = (bb - 1600) * 256 + tid;
        if (i < NLAYER * 768) {
            int l = i / 768, j = i % 768;
            const float* src = j < 256 ? bq : j < 512 ? bk : bv;
            bqkv[i] = src[l * 256 + (j & 255)];
        }
    }
}

// ---------------- degree + edge histogram ----------------
__global__ void degree_hist_kernel(const int* __restrict__ ei,
                                   int* __restrict__ deg_out, int* __restrict__ deg_in,
                                   unsigned* __restrict__ hist) {
    int e = blockIdx.x * 256 + threadIdx.x;
    if (e < NEDGE) {
        int src = ei[e], dst = ei[NEDGE + e];
        atomicAdd(&deg_out[src], 1);
        atomicAdd(&deg_in[dst], 1);
        atomicAdd(&hist[(src >> 6) * 2048 + dst], 1);
    }
}

// ---------------- 3-kernel coalesced parallel scan ----------------
__global__ void edge_scan1_kernel(const unsigned* __restrict__ hist,
                                  unsigned* __restrict__ offsets, unsigned* __restrict__ blocksum) {
    __shared__ unsigned tmp[256];
    int t = threadIdx.x;
    int g = blockIdx.x * 256 + t;
    unsigned v = hist[g];
    tmp[t] = v; __syncthreads();
    for (int off = 1; off < 256; off <<= 1) {
        unsigned u = (t >= off) ? tmp[t - off] : 0;
        __syncthreads();
        tmp[t] += u;
        __syncthreads();
    }
    offsets[g] = tmp[t] - v;
    if (t == 255) blocksum[blockIdx.x] = tmp[255];
}

__global__ void edge_scan2_kernel(unsigned* __restrict__ blocksum) {
    __shared__ unsigned tmp[256];
    int t = threadIdx.x;
    unsigned v = blocksum[t];
    tmp[t] = v; __syncthreads();
    for (int off = 1; off < 256; off <<= 1) {
        unsigned u = (t >= off) ? tmp[t - off] : 0;
        __syncthreads();
        tmp[t] += u;
        __syncthreads();
    }
    blocksum[t] = tmp[t] - v;
}

__global__ void edge_scan3_kernel(const unsigned* __restrict__ blocksum,
                                  unsigned* __restrict__ offsets, unsigned* __restrict__ cursor) {
    int g = blockIdx.x * 256 + threadIdx.x;
    unsigned o = offsets[g] + blocksum[blockIdx.x];
    offsets[g] = o; cursor[g] = o;
    if (g == 0) offsets[65536] = NEDGE;
}

__global__ void edge_scatter_kernel(const int* __restrict__ ei, const int* __restrict__ etypes,
                                    unsigned* __restrict__ cursor, unsigned* __restrict__ packed) {
    int e = blockIdx.x * 256 + threadIdx.x;
    if (e < NEDGE) {
        int src = ei[e], dst = ei[NEDGE + e];
        int key = (src >> 6) * 2048 + dst;
        unsigned pos = atomicAdd(&cursor[key], 1);
        packed[pos] = (unsigned)dst | ((unsigned)(src & 63) << 11) | ((unsigned)etypes[e] << 17);
    }
}

// ---------------- fused centrality + layernorm1 ----------------
__global__ void centrality_ln_kernel(float* __restrict__ h,
                                     const float* __restrict__ din_l,
                                     const float* __restrict__ dout_l,
                                     const int* __restrict__ deg_in,
                                     const int* __restrict__ deg_out,
                                     const float* __restrict__ g,
                                     const float* __restrict__ b,
                                     unsigned short* __restrict__ y) {
    int row = blockIdx.x;
    int tid = threadIdx.x;
    int di = min(max(deg_in[row], 0), MAXDEG);
    int dn = min(max(deg_out[row], 0), MAXDEG);
    float v = h[row * D_MODEL + tid] + din_l[di * D_MODEL + tid] + dout_l[dn * D_MODEL + tid];
    h[row * D_MODEL + tid] = v;
    __shared__ float red[256];
    red[tid] = v; __syncthreads();
    for (int s = 128; s > 0; s >>= 1) { if (tid < s) red[tid] += red[tid + s]; __syncthreads(); }
    float mu = red[0] * (1.0f / D_MODEL);
    __syncthreads();
    float d = v - mu;
    red[tid] = d * d; __syncthreads();
    for (int s = 128; s > 0; s >>= 1) { if (tid < s) red[tid] += red[tid + s]; __syncthreads(); }
    float rstd = rsqrtf(red[0] * (1.0f / D_MODEL) + 1e-5f);
    y[row * D_MODEL + tid] = f2bf(d * rstd * g[tid] + b[tid]);
}

// ---------------- layernorm2 ----------------
__global__ void layernorm_kernel(const float* __restrict__ x,
                                 const float* __restrict__ g,
                                 const float* __restrict__ b,
                                 unsigned short* __restrict__ y) {
    int row = blockIdx.x;
    int tid = threadIdx.x;
    float v = x[row * D_MODEL + tid];
    __shared__ float red[256];
    red[tid] = v; __syncthreads();
    for (int s = 128; s > 0; s >>= 1) { if (tid < s) red[tid] += red[tid + s]; __syncthreads(); }
    float mu = red[0] * (1.0f / D_MODEL);
    __syncthreads();
    float d = v - mu;
    red[tid] = d * d; __syncthreads();
    for (int s = 128; s > 0; s >>= 1) { if (tid < s) red[tid] += red[tid + s]; __syncthreads(); }
    float rstd = rsqrtf(red[0] * (1.0f / D_MODEL) + 1e-5f);
    y[row * D_MODEL + tid] = f2bf(d * rstd * g[tid] + b[tid]);
}

// ---------------- vbt transpose ----------------
__global__ void vbt_t_kernel(const unsigned short* __restrict__ qkvb,
                             unsigned short* __restrict__ vbt) {
    __shared__ unsigned short tile[32][33];
    int c0 = blockIdx.x * 32, r0 = blockIdx.y * 32;
    int tid = threadIdx.x;
    int r = tid >> 3, cg = (tid & 7) * 4;
    u16x4 v4 = *(const u16x4*)&qkvb[(size_t)(r0 + r) * 768 + 512 + c0 + cg];
    tile[r][cg + 0] = v4[0]; tile[r][cg + 1] = v4[1];
    tile[r][cg + 2] = v4[2]; tile[r][cg + 3] = v4[3];
    __syncthreads();
    int c = tid >> 3, rg = (tid & 7) * 4;
    u16x4 o;
    #pragma unroll
    for (int j = 0; j < 4; j++) o[j] = tile[rg + j][c];
    *(u16x4*)&vbt[(size_t)(c0 + c) * N_NODES + r0 + rg] = o;
}

// ---------------- bf16 MFMA GEMM, 32x64 tile, prefetched K-loop ----------------
template <int ACT, bool RESID, bool OUTBF16, bool AFP32>
__global__ void gemm_mfma_kernel(const void* __restrict__ Av,
                                 const unsigned short* __restrict__ Wt,
                                 const float* __restrict__ bias,
                                 float* __restrict__ C, unsigned short* __restrict__ Cb,
                                 int Nc, int K) {
    __shared__ __align__(16) unsigned short As[32][72];
    __shared__ __align__(16) unsigned short Bs[64][72];
    const unsigned short* A16 = (const unsigned short*)Av;
    const float* A32 = (const float*)Av;
    int tid = threadIdx.x;
    int m0 = blockIdx.y * 32, n0 = blockIdx.x * 64;
    int w = tid >> 6, lane = tid & 63;
    int rg = (w & 1) * 16, cg = (w >> 1) * 32;
    int m = lane & 15, quad = lane >> 4;
    f32x4 acc[2] = {{0.f, 0.f, 0.f, 0.f}, {0.f, 0.f, 0.f, 0.f}};
    int ar = tid >> 3, ac = (tid & 7) * 8;
    uint4 ra; float4 fa0, fa1; uint4 rb0, rb1;
    if (AFP32) {
        fa0 = *(const float4*)&A32[(size_t)(m0 + ar) * K + ac];
        fa1 = *(const float4*)&A32[(size_t)(m0 + ar) * K + ac + 4];
    } else {
        ra = *(const uint4*)&A16[(size_t)(m0 + ar) * K + ac];
    }
    rb0 = *(const uint4*)&Wt[(size_t)(n0 + ar) * K + ac];
    rb1 = *(const uint4*)&Wt[(size_t)(n0 + 32 + ar) * K + ac];
    for (int k0 = 0; k0 < K; k0 += 64) {
        if (AFP32) {
            u16x4 t0 = {f2bf(fa0.x), f2bf(fa0.y), f2bf(fa0.z), f2bf(fa0.w)};
            u16x4 t1 = {f2bf(fa1.x), f2bf(fa1.y), f2bf(fa1.z), f2bf(fa1.w)};
            *(u16x4*)&As[ar][ac] = t0;
            *(u16x4*)&As[ar][ac + 4] = t1;
        } else {
            *(uint4*)&As[ar][ac] = ra;
        }
        *(uint4*)&Bs[ar][ac] = rb0;
        *(uint4*)&Bs[ar + 32][ac] = rb1;
        __syncthreads();
        int kn = k0 + 64;
        if (kn < K) {
            if (AFP32) {
                fa0 = *(const float4*)&A32[(size_t)(m0 + ar) * K + kn + ac];
                fa1 = *(const float4*)&A32[(size_t)(m0 + ar) * K + kn + ac + 4];
            } else {
                ra = *(const uint4*)&A16[(size_t)(m0 + ar) * K + kn + ac];
            }
            rb0 = *(const uint4*)&Wt[(size_t)(n0 + ar) * K + kn + ac];
            rb1 = *(const uint4*)&Wt[(size_t)(n0 + 32 + ar) * K + kn + ac];
        }
        #pragma unroll
        for (int ks = 0; ks < 2; ks++) {
            short8 a = *(const short8*)&As[rg + m][ks * 32 + quad * 8];
            #pragma unroll
            for (int t = 0; t < 2; t++) {
                short8 b = *(const short8*)&Bs[cg + t * 16 + m][ks * 32 + quad * 8];
                acc[t] = __builtin_amdgcn_mfma_f32_16x16x32_bf16(a, b, acc[t], 0, 0, 0);
            }
        }
        __syncthreads();
    }
    #pragma unroll
    for (int t = 0; t < 2; t++) {
        #pragma unroll
        for (int reg = 0; reg < 4; reg++) {
            int row = m0 + rg + quad * 4 + reg;
            int col = n0 + cg + t * 16 + m;
            float val = acc[t][reg] + bias[col];
            if (ACT == 1) val = val * 0.5f * (1.0f + erff(val * 0.7071067811865476f));
            size_t idx = (size_t)row * Nc + col;
            if (RESID) val += C[idx];
            if (OUTBF16) Cb[idx] = f2bf(val);
            else C[idx] = val;
        }
    }
}

// ---------------- O-proj GEMM with in-staging merge (no max rescale): h += (ΣO/Σl) @ Wo + bo ----------------
__global__ void gemm_oproj_kernel(const float* __restrict__ part_O,
                                  const float* __restrict__ l_part,
                                  const unsigned short* __restrict__ Wt,
                                  const float* __restrict__ bias,
                                  float* __restrict__ C) {
    __shared__ __align__(16) unsigned short As[32][72];
    __shared__ __align__(16) unsigned short Bs[64][72];
    int tid = threadIdx.x;
    int m0 = blockIdx.y * 32, n0 = blockIdx.x * 64;
    int w = tid >> 6, lane = tid & 63;
    int rg = (w & 1) * 16, cg = (w >> 1) * 32;
    int m = lane & 15, quad = lane >> 4;
    f32x4 acc[2] = {{0.f, 0.f, 0.f, 0.f}, {0.f, 0.f, 0.f, 0.f}};
    int ar = tid >> 3, ac = (tid & 7) * 8;
    int row = m0 + ar;
    for (int k0 = 0; k0 < D_MODEL; k0 += 64) {
        int col = k0 + ac;
        int hh = col >> 5;
        float L = 0.f;
        float o[8] = {0.f, 0.f, 0.f, 0.f, 0.f, 0.f, 0.f, 0.f};
        #pragma unroll
        for (int js = 0; js < JSPLIT; js++) {
            L += l_part[((size_t)js * NHEAD + hh) * N_NODES + row];
            const float* pp = &part_O[((size_t)js * N_NODES + row) * D_MODEL + col];
            float4 p0 = *(const float4*)pp;
            float4 p1 = *(const float4*)(pp + 4);
            o[0] += p0.x; o[1] += p0.y; o[2] += p0.z; o[3] += p0.w;
            o[4] += p1.x; o[5] += p1.y; o[6] += p1.z; o[7] += p1.w;
        }
        float inv = 1.0f / L;
        u16x4 t0, t1;
        #pragma unroll
        for (int j = 0; j < 4; j++) { t0[j] = f2bf(o[j] * inv); t1[j] = f2bf(o[j + 4] * inv); }
        *(u16x4*)&As[ar][ac] = t0;
        *(u16x4*)&As[ar][ac + 4] = t1;
        *(uint4*)&Bs[ar][ac] = *(const uint4*)&Wt[(size_t)(n0 + ar) * D_MODEL + k0 + ac];
        *(uint4*)&Bs[ar + 32][ac] = *(const uint4*)&Wt[(size_t)(n0 + 32 + ar) * D_MODEL + k0 + ac];
        __syncthreads();
        #pragma unroll
        for (int ks = 0; ks < 2; ks++) {
            short8 a = *(const short8*)&As[rg + m][ks * 32 + quad * 8];
            #pragma unroll
            for (int t = 0; t < 2; t++) {
                short8 b = *(const short8*)&Bs[cg + t * 16 + m][ks * 32 + quad * 8];
                acc[t] = __builtin_amdgcn_mfma_f32_16x16x32_bf16(a, b, acc[t], 0, 0, 0);
            }
        }
        __syncthreads();
    }
    #pragma unroll
    for (int t = 0; t < 2; t++) {
        #pragma unroll
        for (int reg = 0; reg < 4; reg++) {
            int orow = m0 + rg + quad * 4 + reg;
            int ocol = n0 + cg + t * 16 + m;
            size_t idx = (size_t)orow * D_MODEL + ocol;
            C[idx] += acc[t][reg] + bias[ocol];
        }
    }
}

// ---------------- bf16 MFMA GEMM, 64x64 tile, prefetched ----------------
template <int ACT>
__global__ void gemm64_kernel(const unsigned short* __restrict__ A,
                              const unsigned short* __restrict__ Wt,
                              const float* __restrict__ bias,
                              unsigned short* __restrict__ Cb,
                              int Nc, int K) {
    __shared__ __align__(16) unsigned short As[64][72];
    __shared__ __align__(16) unsigned short Bs[64][72];
    int tid = threadIdx.x;
    int m0 = blockIdx.y * 64, n0 = blockIdx.x * 64;
    int w = tid >> 6, lane = tid & 63;
    int wr = (w & 1) * 32, wc = (w >> 1) * 32;
    int m = lane & 15, quad = lane >> 4;
    f32x4 acc[2][2] = {{{0.f,0.f,0.f,0.f},{0.f,0.f,0.f,0.f}},{{0.f,0.f,0.f,0.f},{0.f,0.f,0.f,0.f}}};
    int sr = tid >> 2, sg = (tid & 3) * 16;
    uint4 a0 = *(const uint4*)&A[(size_t)(m0 + sr) * K + sg];
    uint4 a1 = *(const uint4*)&A[(size_t)(m0 + sr) * K + sg + 8];
    uint4 b0 = *(const uint4*)&Wt[(size_t)(n0 + sr) * K + sg];
    uint4 b1 = *(const uint4*)&Wt[(size_t)(n0 + sr) * K + sg + 8];
    for (int k0 = 0; k0 < K; k0 += 64) {
        *(uint4*)&As[sr][sg] = a0;
        *(uint4*)&As[sr][sg + 8] = a1;
        *(uint4*)&Bs[sr][sg] = b0;
        *(uint4*)&Bs[sr][sg + 8] = b1;
        __syncthreads();
        int kn = k0 + 64;
        if (kn < K) {
            a0 = *(const uint4*)&A[(size_t)(m0 + sr) * K + kn + sg];
            a1 = *(const uint4*)&A[(size_t)(m0 + sr) * K + kn + sg + 8];
            b0 = *(const uint4*)&Wt[(size_t)(n0 + sr) * K + kn + sg];
            b1 = *(const uint4*)&Wt[(size_t)(n0 + sr) * K + kn + sg + 8];
        }
        #pragma unroll
        for (int kh = 0; kh < 2; kh++) {
            short8 x0 = *(const short8*)&As[wr + m][kh * 32 + quad * 8];
            short8 x1 = *(const short8*)&As[wr + 16 + m][kh * 32 + quad * 8];
            short8 y0 = *(const short8*)&Bs[wc + m][kh * 32 + quad * 8];
            short8 y1 = *(const short8*)&Bs[wc + 16 + m][kh * 32 + quad * 8];
            acc[0][0] = __builtin_amdgcn_mfma_f32_16x16x32_bf16(x0, y0, acc[0][0], 0, 0, 0);
            acc[0][1] = __builtin_amdgcn_mfma_f32_16x16x32_bf16(x0, y1, acc[0][1], 0, 0, 0);
            acc[1][0] = __builtin_amdgcn_mfma_f32_16x16x32_bf16(x1, y0, acc[1][0], 0, 0, 0);
            acc[1][1] = __builtin_amdgcn_mfma_f32_16x16x32_bf16(x1, y1, acc[1][1], 0, 0, 0);
        }
        __syncthreads();
    }
    #pragma unroll
    for (int mt = 0; mt < 2; mt++) {
        #pragma unroll
        for (int nt = 0; nt < 2; nt++) {
            #pragma unroll
            for (int reg = 0; reg < 4; reg++) {
                int row = m0 + wr + mt * 16 + quad * 4 + reg;
                int col = n0 + wc + nt * 16 + m;
                float val = acc[mt][nt][reg] + bias[col];
                if (ACT == 1) val = val * 0.5f * (1.0f + erff(val * 0.7071067811865476f));
                Cb[(size_t)row * Nc + col] = f2bf(val);
            }
        }
    }
}

// ---------------- flash attention: NO max subtraction (scores bounded, fp32-safe) ----------------
// grid (N/64, H, JSPLIT), block 256 = 4 waves; wave w owns rows w*16..+16.
__global__ __launch_bounds__(256)
void flash_attn_kernel(const unsigned short* __restrict__ qkvb,
                       const unsigned short* __restrict__ vbt,
                       const unsigned char* __restrict__ bucket,
                       const float* __restrict__ spd_l,
                       const float* __restrict__ et_l,
                       const unsigned* __restrict__ offsets,
                       const unsigned* __restrict__ packed,
                       float* __restrict__ part_O,
                       float* __restrict__ l_part) {
    __shared__ __align__(16) unsigned short ks[64][40];
    __shared__ __align__(16) unsigned short vs[32][72];
    __shared__ __align__(16) float ov[64][68];
    __shared__ float et[8];

    int tid = threadIdx.x;
    int rb = blockIdx.x;
    int i0 = rb * 64;
    int hh = blockIdx.y;
    int js = blockIdx.z;
    int lane = tid & 63;
    if (tid < 8) et[tid] = et_l[tid * NHEAD + hh];
    float spd_reg = spd_l[(lane < 11 ? lane : 10) * NHEAD + hh];

    int w = tid >> 6;
    int m = lane & 15, quad = lane >> 4;
    int r0 = w * 16;
    short8 aq = *(const short8*)&qkvb[(size_t)(i0 + r0 + m) * 768 + hh * DH + quad * 8];
    float l_st[4] = {0.f, 0.f, 0.f, 0.f};
    f32x4 oacc[2] = {{0.f, 0.f, 0.f, 0.f}, {0.f, 0.f, 0.f, 0.f}};
    const float scale = 0.17677669529663687f;

    int krow = tid >> 2, kcol = (tid & 3) * 8;
    int vrow = tid >> 3, vcol = (tid & 7) * 8;
    int brow = tid >> 2, bcol = (tid & 3) * 16;

    for (int jt = 0; jt < N_NODES / JSPLIT / 64; jt++) {
        int j0 = js * (N_NODES / JSPLIT) + jt * 64;
        __syncthreads();
        *(uint4*)&ks[krow][kcol] =
            *(const uint4*)&qkvb[(size_t)(j0 + krow) * 768 + 256 + hh * DH + kcol];
        *(uint4*)&vs[vrow][vcol] =
            *(const uint4*)&vbt[(size_t)(hh * DH + vrow) * N_NODES + j0 + vcol];
        {
            uint4 b16 = *(const uint4*)&bucket[(size_t)(i0 + brow) * N_NODES + j0 + bcol];
            const unsigned char* bb = (const unsigned char*)&b16;
            float fb[16];
            #pragma unroll
            for (int i = 0; i < 16; i++)
                fb[i] = __int_as_float(
                    __builtin_amdgcn_ds_bpermute(((int)bb[i]) << 2, __float_as_int(spd_reg)));
            #pragma unroll
            for (int g = 0; g < 4; g++) {
                f32x4 st = {fb[g * 4], fb[g * 4 + 1], fb[g * 4 + 2], fb[g * 4 + 3]};
                *(f32x4*)&ov[brow][bcol + g * 4] = st;
            }
        }
        __syncthreads();
        {
            unsigned key0 = (unsigned)rb * 2048 + j0;
            unsigned start = offsets[key0], end = offsets[key0 + 64];
            for (unsigned i = start + tid; i < end; i += 256) {
                unsigned p = packed[i];
                atomicAdd(&ov[(p >> 11) & 63][(p & 2047) - j0], et[(p >> 17) & 7]);
            }
        }
        __syncthreads();
        // S then P = exp(S) directly — no running max (|S| bounded ~10, fp32-safe)
        float sv[4][4];
        #pragma unroll
        for (int t = 0; t < 4; t++) {
            short8 bk8 = *(const short8*)&ks[t * 16 + m][quad * 8];
            f32x4 z = {0.f, 0.f, 0.f, 0.f};
            f32x4 sacc = __builtin_amdgcn_mfma_f32_16x16x32_bf16(aq, bk8, z, 0, 0, 0);
            #pragma unroll
            for (int r = 0; r < 4; r++)
                sv[t][r] = __expf(sacc[r] * scale + ov[r0 + quad * 4 + r][t * 16 + m]);
        }
        // row sums via DPP (16-lane rows)
        #pragma unroll
        for (int r = 0; r < 4; r++) {
            float ps = sv[0][r] + sv[1][r] + sv[2][r] + sv[3][r];
            ps += dpp_ror<0x121>(ps);
            ps += dpp_ror<0x122>(ps);
            ps += dpp_ror<0x124>(ps);
            ps += dpp_ror<0x128>(ps);
            l_st[r] += ps;
        }
        // float P into own wave's rows of ov
        #pragma unroll
        for (int t = 0; t < 4; t++)
            #pragma unroll
            for (int r = 0; r < 4; r++)
                ov[r0 + quad * 4 + r][t * 16 + m] = sv[t][r];
        __builtin_amdgcn_s_waitcnt(0xC07F);   // lgkmcnt(0): own-wave P writes visible
        #pragma unroll
        for (int kh = 0; kh < 2; kh++) {
            f32x4 p0 = *(const f32x4*)&ov[r0 + m][kh * 32 + quad * 8];
            f32x4 p1 = *(const f32x4*)&ov[r0 + m][kh * 32 + quad * 8 + 4];
            short8 pa;
            pa[0] = (short)f2bf(p0[0]); pa[1] = (short)f2bf(p0[1]);
            pa[2] = (short)f2bf(p0[2]); pa[3] = (short)f2bf(p0[3]);
            pa[4] = (short)f2bf(p1[0]); pa[5] = (short)f2bf(p1[1]);
            pa[6] = (short)f2bf(p1[2]); pa[7] = (short)f2bf(p1[3]);
            #pragma unroll
            for (int t = 0; t < 2; t++) {
                short8 vb = *(const short8*)&vs[t * 16 + m][kh * 32 + quad * 8];
                oacc[t] = __builtin_amdgcn_mfma_f32_16x16x32_bf16(pa, vb, oacc[t], 0, 0, 0);
            }
        }
    }
    #pragma unroll
    for (int t = 0; t < 2; t++)
        #pragma unroll
        for (int r = 0; r < 4; r++)
            part_O[((size_t)js * N_NODES + i0 + r0 + quad * 4 + r) * D_MODEL + hh * DH + t * 16 + m] =
                oacc[t][r];
    if (m == 0) {
        #pragma unroll
        for (int r = 0; r < 4; r++) {
            int row = i0 + r0 + quad * 4 + r;
            l_part[((size_t)js * NHEAD + hh) * N_NODES + row] = l_st[r];
        }
    }
}

// 256-byte-aligned workspace allocation
#define WS_ALLOC(type, name, count) \
    type* name = (type*)base; base += (((size_t)(count) * sizeof(type)) + 255) & ~(size_t)255;

extern "C" void kernel_launch(void* const* d_in, const int* in_sizes, int n_in,
                              void* d_out, int out_size, void* d_ws, size_t ws_size,
                              hipStream_t stream) {
    const float* x          = (const float*)d_in[0];
    const int*   edge_index = (const int*)d_in[1];
    const int*   edge_types = (const int*)d_in[2];
    const float* pos        = (const float*)d_in[3];
    const float* W_emb      = (const float*)d_in[4];
    const float* b_emb      = (const float*)d_in[5];
    const float* Wq         = (const float*)d_in[6];
    const float* Wk         = (const float*)d_in[7];
    const float* Wv         = (const float*)d_in[8];
    const float* Wo         = (const float*)d_in[9];
    const float* bq         = (const float*)d_in[10];
    const float* bk         = (const float*)d_in[11];
    const float* bv         = (const float*)d_in[12];
    const float* bo         = (const float*)d_in[13];
    const float* spd_table  = (const float*)d_in[14];
    const float* edge_table = (const float*)d_in[15];
    const float* din_emb    = (const float*)d_in[16];
    const float* dout_emb   = (const float*)d_in[17];
    const float* ln1_g      = (const float*)d_in[18];
    const float* ln1_b      = (const float*)d_in[19];
    const float* ln2_g      = (const float*)d_in[20];
    const float* ln2_b      = (const float*)d_in[21];
    const float* W1         = (const float*)d_in[22];
    const float* b1         = (const float*)d_in[23];
    const float* W2         = (const float*)d_in[24];
    const float* b2         = (const float*)d_in[25];
    const float* W_out      = (const float*)d_in[26];
    const float* b_out      = (const float*)d_in[27];
    float* out = (float*)d_out;

    char* base = (char*)d_ws;
    WS_ALLOC(int, deg_out, N_NODES)
    WS_ALLOC(int, deg_in, N_NODES)
    WS_ALLOC(float, h, N_NODES * D_MODEL)
    WS_ALLOC(unsigned short, xb, N_NODES * D_MODEL)
    WS_ALLOC(unsigned short, qkvb, N_NODES * 768)
    WS_ALLOC(unsigned short, vbt, D_MODEL * N_NODES)
    WS_ALLOC(unsigned short, ffnb, N_NODES * D_FF)
    WS_ALLOC(unsigned char, bucket, (size_t)N_NODES * N_NODES)
    WS_ALLOC(unsigned short, qkvt, NLAYER * 768 * D_MODEL)
    WS_ALLOC(unsigned short, wot, NLAYER * D_MODEL * D_MODEL)
    WS_ALLOC(unsigned short, w1t, NLAYER * D_MODEL * D_FF)
    WS_ALLOC(unsigned short, w2t, NLAYER * D_FF * D_MODEL)
    WS_ALLOC(unsigned short, wembt, D_FEAT * D_MODEL)
    WS_ALLOC(unsigned short, woutt, D_MODEL * D_OUT)
    WS_ALLOC(float, bqkv, NLAYER * 768)
    WS_ALLOC(unsigned, hist, 65536)
    WS_ALLOC(unsigned, offsets, 65537)
    WS_ALLOC(unsigned, cursor, 65536)
    WS_ALLOC(unsigned, blocksum, 256)
    WS_ALLOC(unsigned, packed, NEDGE)
    WS_ALLOC(float, part_O, (size_t)JSPLIT * N_NODES * D_MODEL)
    WS_ALLOC(float, l_part, (size_t)JSPLIT * NHEAD * N_NODES)

    // ---- prep ----
    mega_prep_kernel<<<5702, 256, 0, stream>>>(pos, bucket, hist, deg_out, deg_in,
                                               Wq, Wk, Wv, Wo, W1, W2, W_emb, W_out,
                                               bq, bk, bv, qkvt, wot, w1t, w2t, wembt, woutt, bqkv);
    degree_hist_kernel<<<NEDGE / 256, 256, 0, stream>>>(edge_index, deg_out, deg_in, hist);
    edge_scan1_kernel<<<256, 256, 0, stream>>>(hist, offsets, blocksum);
    edge_scan2_kernel<<<1, 256, 0, stream>>>(blocksum);
    edge_scan3_kernel<<<256, 256, 0, stream>>>(blocksum, offsets, cursor);
    edge_scatter_kernel<<<NEDGE / 256, 256, 0, stream>>>(edge_index, edge_types, cursor, packed);

    // embed: h = x @ W_emb + b_emb (fp32 A, cast in staging)
    gemm_mfma_kernel<0, false, false, true><<<dim3(D_MODEL / 64, N_NODES / 32), 256, 0, stream>>>(
        x, wembt, b_emb, h, nullptr, D_MODEL, D_FEAT);

    for (int l = 0; l < NLAYER; l++) {
        centrality_ln_kernel<<<N_NODES, 256, 0, stream>>>(
            h, din_emb + (size_t)l * (MAXDEG + 1) * D_MODEL,
            dout_emb + (size_t)l * (MAXDEG + 1) * D_MODEL, deg_in, deg_out,
            ln1_g + l * D_MODEL, ln1_b + l * D_MODEL, xb);

        gemm64_kernel<0><<<dim3(768 / 64, N_NODES / 64), 256, 0, stream>>>(
            xb, qkvt + (size_t)l * 768 * D_MODEL, bqkv + l * 768, qkvb, 768, D_MODEL);

        vbt_t_kernel<<<dim3(D_MODEL / 32, N_NODES / 32), 256, 0, stream>>>(qkvb, vbt);

        flash_attn_kernel<<<dim3(N_NODES / 64, NHEAD, JSPLIT), 256, 0, stream>>>(
            qkvb, vbt, bucket, spd_table + (size_t)l * 11 * NHEAD,
            edge_table + (size_t)l * 8 * NHEAD, offsets, packed, part_O, l_part);

        gemm_oproj_kernel<<<dim3(D_MODEL / 64, N_NODES / 32), 256, 0, stream>>>(
            part_O, l_part, wot + (size_t)l * D_MODEL * D_MODEL, bo + l * D_MODEL, h);

        layernorm_kernel<<<N_NODES, 256, 0, stream>>>(h, ln2_g + l * D_MODEL, ln2_b + l * D_MODEL, xb);

        gemm64_kernel<1><<<dim3(D_FF / 64, N_NODES / 64), 256, 0, stream>>>(
            xb, w1t + (size_t)l * D_MODEL * D_FF, b1 + l * D_FF, ffnb, D_FF, D_MODEL);

        gemm_mfma_kernel<0, true, false, false><<<dim3(D_MODEL / 64, N_NODES / 32), 256, 0, stream>>>(
            ffnb, w2t + (size_t)l * D_FF * D_MODEL, b2 + l * D_MODEL, h, nullptr, D_MODEL, D_FF);
    }

    // final: out = h @ W_out + b_out (fp32 A, cast in staging)
    gemm_mfma_kernel<0, false, false, true><<<dim3(D_OUT / 64, N_NODES / 32), 256, 0, stream>>>(
        h, woutt, b_out, out, nullptr, D_OUT, D_MODEL);
}